// Round 11
// baseline (246.088 us; speedup 1.0000x reference)
//
#include <hip/hip_runtime.h>
#include <hip/hip_bf16.h>
#include <stdint.h>

constexpr int FN   = 64;
constexpr int HIDN = 32;
constexpr int FMSG = 64;
constexpr int FOUT = 128;

using short8 = __attribute__((ext_vector_type(8))) short;
using f32x4  = __attribute__((ext_vector_type(4))) float;

union Frag { short8 v; uint32_t u[4]; };

__device__ __forceinline__ uint32_t packrn(float a, float b) {
    union { __hip_bfloat162 h; uint32_t u; } cv;
    cv.h = __float22bfloat162_rn(make_float2(a, b));   // v_cvt_pk_bf16_f32
    return cv.u;
}
__device__ __forceinline__ float bf16_to_f(uint32_t h16) {
    return __uint_as_float(h16 << 16);
}

__device__ __forceinline__ int node_of(const int* __restrict__ offs, int N, int target) {
    int l = 0, r = N + 1;
    while (l + 1 < r) {
        const int m = (l + r) >> 1;
        if (offs[m] <= target) l = m; else r = m;
    }
    return l;
}

// ---------------------------------------------------------------------------
__global__ __launch_bounds__(256) void zero_cnt_kernel(int* __restrict__ cnt, int N)
{
    const int i = blockIdx.x * 256 + threadIdx.x;
    if (i < N) cnt[i] = 0;
}

// ---------------------------------------------------------------------------
// hist: 1 edge/thread (3125 blocks -> max outstanding atomics).
// ---------------------------------------------------------------------------
__global__ __launch_bounds__(256) void hist_kernel(
    const int* __restrict__ ei, int* __restrict__ cnt, int* __restrict__ rank,
    int E)
{
    const int e = blockIdx.x * 256 + threadIdx.x;
    if (e < E) rank[e] = atomicAdd(cnt + ei[E + e], 1);
}

// ---------------------------------------------------------------------------
// node_pre: wave-cooperative, LDS-staged coalesced x reads.
// 128 threads = 2 waves; each wave: 64 nodes. Barrier-free (wave-local LDS).
// ---------------------------------------------------------------------------
__global__ __launch_bounds__(128) void node_pre_kernel(
    const float* __restrict__ x,
    const float* __restrict__ W1, const float* __restrict__ b1,
    const float* __restrict__ W3, const float* __restrict__ b3,
    float* __restrict__ Pa, float* __restrict__ Pb, float* __restrict__ Qc,
    int N)
{
    __shared__ float xs_all[2 * 64 * 65];
    const int w    = threadIdx.x >> 6;
    const int lane = threadIdx.x & 63;
    float* xs = xs_all + w * (64 * 65);
    const int nbase = blockIdx.x * 128 + w * 64;
    if (nbase >= N) return;

    // ---- stage 64 rows x 64 floats, coalesced (consecutive lanes -> consecutive float4)
#pragma unroll
    for (int j = 0; j < 16; ++j) {
        const int idx = j * 64 + lane;          // float4 index within tile
        const int row = idx >> 4, cq = idx & 15;
        const int nr  = min(nbase + row, N - 1);
        const float4 v = *reinterpret_cast<const float4*>(x + (size_t)nr * FN + cq * 4);
        float* d = xs + row * 65 + cq * 4;
        d[0] = v.x; d[1] = v.y; d[2] = v.z; d[3] = v.w;
    }

    const int n = nbase + lane;
    if (n >= N) return;

    float a[HIDN], bq[HIDN], c[HIDN];
#pragma unroll
    for (int j = 0; j < HIDN; ++j) { a[j] = b1[j]; bq[j] = 0.0f; c[j] = b3[j]; }
    const float* xr = xs + lane * 65;           // 2-way bank alias (free)
    const float* WA = W1;
    const float* WB = W1 + FN * HIDN;
    const float* WX = W3;                       // rows 0..63 of W3
#pragma unroll 2
    for (int k = 0; k < FN; k += 4) {
        const float v0 = xr[k], v1 = xr[k + 1], v2 = xr[k + 2], v3 = xr[k + 3];
        const float* wa = WA + k * HIDN;
        const float* wb = WB + k * HIDN;
        const float* wc = WX + k * HIDN;
#pragma unroll
        for (int j = 0; j < HIDN; ++j) {
            float aj = a[j], bj = bq[j], cj = c[j];
            aj = fmaf(v0, wa[j], aj);            bj = fmaf(v0, wb[j], bj);            cj = fmaf(v0, wc[j], cj);
            aj = fmaf(v1, wa[HIDN + j], aj);     bj = fmaf(v1, wb[HIDN + j], bj);     cj = fmaf(v1, wc[HIDN + j], cj);
            aj = fmaf(v2, wa[2 * HIDN + j], aj); bj = fmaf(v2, wb[2 * HIDN + j], bj); cj = fmaf(v2, wc[2 * HIDN + j], cj);
            aj = fmaf(v3, wa[3 * HIDN + j], aj); bj = fmaf(v3, wb[3 * HIDN + j], bj); cj = fmaf(v3, wc[3 * HIDN + j], cj);
            a[j] = aj; bq[j] = bj; c[j] = cj;
        }
    }
    float4* pa = reinterpret_cast<float4*>(Pa + (size_t)n * HIDN);
    float4* pb = reinterpret_cast<float4*>(Pb + (size_t)n * HIDN);
    float4* qc = reinterpret_cast<float4*>(Qc + (size_t)n * HIDN);
#pragma unroll
    for (int q = 0; q < HIDN / 4; ++q) {
        pa[q] = make_float4(a[4*q], a[4*q+1], a[4*q+2], a[4*q+3]);
        pb[q] = make_float4(bq[4*q], bq[4*q+1], bq[4*q+2], bq[4*q+3]);
        qc[q] = make_float4(c[4*q], c[4*q+1], c[4*q+2], c[4*q+3]);
    }
}

// ---------------------------------------------------------------------------
// prep_tail: [0] pack weights + Qu | [1, 1+BZ) agg zero (grid-stride uint4)
// ---------------------------------------------------------------------------
__global__ __launch_bounds__(256) void prep_tail_kernel(
    const float* __restrict__ u,
    const float* __restrict__ W1, const float* __restrict__ W2,
    const float* __restrict__ W3, const float* __restrict__ W4,
    float* __restrict__ Qu,
    uint32_t* __restrict__ PW1, uint32_t* __restrict__ PW2,
    uint32_t* __restrict__ PW3, uint32_t* __restrict__ PW4,
    uint4* __restrict__ zbase, size_t zquads,
    int G, int BZ)
{
    const int b   = blockIdx.x;
    const int tid = threadIdx.x;

    if (b == 0) {
        const float* WC = W1 + 2 * FN * HIDN;
        for (int i = tid; i < 1024; i += 256) {          // PW1[j<32][k2<32]
            const int j = i >> 5, k2 = i & 31;
            PW1[i] = packrn(WC[(2 * k2) * HIDN + j], WC[(2 * k2 + 1) * HIDN + j]);
        }
        for (int i = tid; i < 1024; i += 256) {          // PW2[j<64][k2<16]
            const int j = i >> 4, k2 = i & 15;
            PW2[i] = packrn(W2[(2 * k2) * FMSG + j], W2[(2 * k2 + 1) * FMSG + j]);
        }
        const float* W3m = W3 + 64 * HIDN;               // rows 64..191 (mean|max)
        for (int i = tid; i < 2048; i += 256) {          // PW3[j<32][k2<64]
            const int j = i >> 6, k2 = i & 63;
            PW3[i] = packrn(W3m[(2 * k2) * HIDN + j], W3m[(2 * k2 + 1) * HIDN + j]);
        }
        for (int i = tid; i < 2048; i += 256) {          // PW4[j<128][k2<16]
            const int j = i >> 4, k2 = i & 15;
            PW4[i] = packrn(W4[(2 * k2) * FOUT + j], W4[(2 * k2 + 1) * FOUT + j]);
        }
        const float* W3u = W3 + 192 * HIDN;              // rows 192..255 (u part)
        for (int i = tid; i < G * HIDN; i += 256) {      // Qu[g][j]
            const int g = i >> 5, j = i & 31;
            const float* ur = u + (size_t)g * FN;
            float acc = 0.0f;
#pragma unroll 8
            for (int k = 0; k < FN; ++k) acc = fmaf(ur[k], W3u[k * HIDN + j], acc);
            Qu[i] = acc;
        }
        return;
    }
    const size_t stride = (size_t)BZ * 256;
    const uint4 z = make_uint4(0u, 0u, 0u, 0u);
    for (size_t i = (size_t)(b - 1) * 256 + tid; i < zquads; i += stride)
        zbase[i] = z;
}

// ---------------------------------------------------------------------------
// Multi-block scan over cnt[N] -> offs[N+1]
// ---------------------------------------------------------------------------
__global__ __launch_bounds__(256) void scanA_kernel(
    const int* __restrict__ cnt, int* __restrict__ part, int N)
{
    __shared__ int red[256];
    const int tid  = threadIdx.x;
    const int base = blockIdx.x * 2048 + tid * 8;
    int s = 0;
    if (base + 8 <= N) {
        const int4 a = *reinterpret_cast<const int4*>(cnt + base);
        const int4 b = *reinterpret_cast<const int4*>(cnt + base + 4);
        s = a.x + a.y + a.z + a.w + b.x + b.y + b.z + b.w;
    } else {
        for (int i = base; i < min(base + 8, N); ++i) s += cnt[i];
    }
    red[tid] = s;
    __syncthreads();
    for (int d = 128; d > 0; d >>= 1) {
        if (tid < d) red[tid] += red[tid + d];
        __syncthreads();
    }
    if (tid == 0) part[blockIdx.x] = red[0];
}

__global__ __launch_bounds__(64) void scanB_kernel(
    const int* __restrict__ part, int* __restrict__ partx,
    int* __restrict__ offs, int NB, int N)
{
    if (threadIdx.x == 0) {
        int run = 0;
        for (int i = 0; i < NB; ++i) { partx[i] = run; run += part[i]; }
        offs[N] = run;
    }
}

__global__ __launch_bounds__(256) void scanC_kernel(
    const int* __restrict__ cnt, const int* __restrict__ partx,
    int* __restrict__ offs, int N)
{
    __shared__ int sb[256];
    const int tid  = threadIdx.x;
    const int base = blockIdx.x * 2048 + tid * 8;
    int v[8];
    int tsum = 0;
#pragma unroll
    for (int q = 0; q < 8; ++q) {
        const int i = base + q;
        v[q] = (i < N) ? cnt[i] : 0;
        tsum += v[q];
    }
    sb[tid] = tsum;
    __syncthreads();
    for (int d = 1; d < 256; d <<= 1) {
        const int t = (tid >= d) ? sb[tid - d] : 0;
        __syncthreads();
        sb[tid] += t;
        __syncthreads();
    }
    int run = partx[blockIdx.x] + sb[tid] - tsum;
#pragma unroll
    for (int q = 0; q < 8; ++q) {
        const int i = base + q;
        if (i < N) offs[i] = run;
        run += v[q];
    }
}

// ---------------------------------------------------------------------------
// scatter (blocks [0,SB)) + ntile builder (blocks [SB, SB+TB))
// ---------------------------------------------------------------------------
__global__ __launch_bounds__(256) void scatter_ntile_kernel(
    const int* __restrict__ ei, const int* __restrict__ offs,
    const int* __restrict__ rank, int4* __restrict__ re4,
    int2* __restrict__ ntile, int E, int N, int NT, int SB)
{
    const int tid = threadIdx.x;
    if ((int)blockIdx.x < SB) {
        const int e = blockIdx.x * 256 + tid;
        if (e >= E) return;
        const int row = ei[e];
        const int col = ei[E + e];
        const int pos = offs[col] + rank[e];
        re4[pos] = make_int4(row, col, e, 0);
    } else {
        const int t = ((int)blockIdx.x - SB) * 256 + tid;
        if (t >= NT) return;
        const int a = node_of(offs, N, t * 64);
        const int b = node_of(offs, N, min(t * 64 + 63, E - 1));
        ntile[t] = make_int2(a, b);
    }
}

// ---------------------------------------------------------------------------
// Barrier-free MFMA fused edge kernel: 1 wave = 64 sorted edges (unchanged).
// ---------------------------------------------------------------------------
__global__ __launch_bounds__(128) void fused_edge_mfma(
    const float* __restrict__ ea,
    const uint32_t* __restrict__ PW1, const uint32_t* __restrict__ PW2,
    const float* __restrict__ b2,
    const float* __restrict__ Pa, const float* __restrict__ Pb,
    const int4* __restrict__ re4, const int* __restrict__ offs,
    const int2* __restrict__ ntile,
    float* __restrict__ agg_sum, int* __restrict__ agg_maxb,
    int N, int E, int NT)
{
    __shared__ uint32_t smem_all[2 * 64 * 34];
    const int w    = threadIdx.x >> 6;
    const int t    = blockIdx.x * 2 + w;
    if (t >= NT) return;
    uint32_t* smem = smem_all + w * (64 * 34);
    const int lane = threadIdx.x & 63;
    const int l15  = lane & 15;
    const int l4   = lane >> 4;
    const int e0   = t * 64;
    const int e1   = min(e0 + 64, E);
    const int2 nrange = ntile[t];

    const int p = e0 + lane;
    const int4 rce = re4[min(p, E - 1)];
    {
        const float2* pa = reinterpret_cast<const float2*>(Pa + (size_t)rce.x * HIDN);
        const float2* pb = reinterpret_cast<const float2*>(Pb + (size_t)rce.y * HIDN);
        float2* dst = reinterpret_cast<float2*>(&smem[lane * 34]);
#pragma unroll
        for (int q = 0; q < 16; ++q) {
            const float2 a = pa[q], b = pb[q];
            dst[q] = make_float2(a.x + b.x, a.y + b.y);
        }
    }

    Frag B1[2][2];
#pragma unroll
    for (int nt = 0; nt < 2; ++nt)
#pragma unroll
        for (int ks = 0; ks < 2; ++ks) {
            const uint4 q = *reinterpret_cast<const uint4*>(
                &PW1[(nt * 16 + l15) * 32 + ks * 16 + l4 * 4]);
            B1[nt][ks].u[0] = q.x; B1[nt][ks].u[1] = q.y;
            B1[nt][ks].u[2] = q.z; B1[nt][ks].u[3] = q.w;
        }
    Frag B2f[4];
#pragma unroll
    for (int nt = 0; nt < 4; ++nt) {
        const uint4 q = *reinterpret_cast<const uint4*>(
            &PW2[(nt * 16 + l15) * 16 + l4 * 4]);
        B2f[nt].u[0] = q.x; B2f[nt].u[1] = q.y;
        B2f[nt].u[2] = q.z; B2f[nt].u[3] = q.w;
    }

    Frag A1[4][2];
#pragma unroll
    for (int mt = 0; mt < 4; ++mt) {
        const int eix = __shfl(rce.z, mt * 16 + l15, 64);
        const float* rp = ea + (size_t)eix * FN;
#pragma unroll
        for (int ks = 0; ks < 2; ++ks) {
            const float4* gp = reinterpret_cast<const float4*>(rp + ks * 32 + l4 * 8);
            const float4 f0 = gp[0], f1 = gp[1];
            A1[mt][ks].u[0] = packrn(f0.x, f0.y);
            A1[mt][ks].u[1] = packrn(f0.z, f0.w);
            A1[mt][ks].u[2] = packrn(f1.x, f1.y);
            A1[mt][ks].u[3] = packrn(f1.z, f1.w);
        }
    }

    f32x4 acc1[4][2];
    const float* Pl = reinterpret_cast<const float*>(smem);
#pragma unroll
    for (int mt = 0; mt < 4; ++mt)
#pragma unroll
        for (int nt = 0; nt < 2; ++nt)
#pragma unroll
            for (int r = 0; r < 4; ++r) {
                const int et = mt * 16 + l4 * 4 + r;
                acc1[mt][nt][r] = Pl[et * 34 + nt * 16 + l15];
            }
#pragma unroll
    for (int mt = 0; mt < 4; ++mt)
#pragma unroll
        for (int nt = 0; nt < 2; ++nt)
#pragma unroll
            for (int ks = 0; ks < 2; ++ks)
                acc1[mt][nt] = __builtin_amdgcn_mfma_f32_16x16x32_bf16(
                    A1[mt][ks].v, B1[nt][ks].v, acc1[mt][nt], 0, 0, 0);

    float* Hl = reinterpret_cast<float*>(smem);
#pragma unroll
    for (int mt = 0; mt < 4; ++mt)
#pragma unroll
        for (int nt = 0; nt < 2; ++nt)
#pragma unroll
            for (int r = 0; r < 4; ++r) {
                const int et = mt * 16 + l4 * 4 + r;
                Hl[et * 34 + nt * 16 + l15] = fmaxf(acc1[mt][nt][r], 0.0f);
            }

    Frag A2[4];
#pragma unroll
    for (int mt = 0; mt < 4; ++mt) {
        const float* hb = &Hl[(mt * 16 + l15) * 34 + l4 * 8];
        const float2 g0 = *reinterpret_cast<const float2*>(hb + 0);
        const float2 g1 = *reinterpret_cast<const float2*>(hb + 2);
        const float2 g2 = *reinterpret_cast<const float2*>(hb + 4);
        const float2 g3 = *reinterpret_cast<const float2*>(hb + 6);
        A2[mt].u[0] = packrn(g0.x, g0.y);
        A2[mt].u[1] = packrn(g1.x, g1.y);
        A2[mt].u[2] = packrn(g2.x, g2.y);
        A2[mt].u[3] = packrn(g3.x, g3.y);
    }

#pragma unroll
    for (int nt = 0; nt < 4; ++nt) {
        const float b2v = b2[nt * 16 + l15];
        f32x4 a2c[4];
#pragma unroll
        for (int mt = 0; mt < 4; ++mt) {
            a2c[mt] = (f32x4){0.f, 0.f, 0.f, 0.f};
            a2c[mt] = __builtin_amdgcn_mfma_f32_16x16x32_bf16(
                A2[mt].v, B2f[nt].v, a2c[mt], 0, 0, 0);
        }
        const int j = nt * 16 + l15;
#pragma unroll
        for (int mt = 0; mt < 4; ++mt)
#pragma unroll
            for (int rp2 = 0; rp2 < 2; ++rp2) {
                const int q2 = mt * 8 + l4 * 2 + rp2;
                const float v0 = fmaxf(a2c[mt][rp2 * 2]     + b2v, 0.0f);
                const float v1 = fmaxf(a2c[mt][rp2 * 2 + 1] + b2v, 0.0f);
                smem[q2 * 64 + (j ^ (((q2 >> 1) & 1) << 4))] = packrn(v0, v1);
            }
    }

    const int n0 = nrange.x, n1 = nrange.y;
    for (int n = n0; n <= n1; ++n) {
        const int s0 = offs[n], t0 = offs[n + 1];
        const int sl = max(s0, e0) - e0, tl = min(t0, e1) - e0;
        float sum = 0.0f, mx = 0.0f;
        int q = sl;
        if (q < tl && (q & 1)) {
            const int q2 = q >> 1;
            const uint32_t wv = smem[q2 * 64 + (lane ^ (((q2 >> 1) & 1) << 4))];
            const float v = bf16_to_f(wv >> 16);
            sum += v; mx = fmaxf(mx, v); ++q;
        }
        for (; q + 1 < tl; q += 2) {
            const int q2 = q >> 1;
            const uint32_t wv = smem[q2 * 64 + (lane ^ (((q2 >> 1) & 1) << 4))];
            const float v0 = bf16_to_f(wv & 0xffffu), v1 = bf16_to_f(wv >> 16);
            sum += v0 + v1; mx = fmaxf(mx, fmaxf(v0, v1));
        }
        if (q < tl) {
            const int q2 = q >> 1;
            const uint32_t wv = smem[q2 * 64 + (lane ^ (((q2 >> 1) & 1) << 4))];
            const float v = bf16_to_f(wv & 0xffffu);
            sum += v; mx = fmaxf(mx, v);
        }
        float* sp = agg_sum  + (size_t)n * FMSG + lane;
        int*   mp = agg_maxb + (size_t)n * FMSG + lane;
        if (s0 >= e0 && t0 <= e1) {
            *sp = sum;
            *mp = __float_as_int(mx);
        } else {
            unsafeAtomicAdd(sp, sum);
            atomicMax(mp, __float_as_int(mx));
        }
    }
}

// ---------------------------------------------------------------------------
// Barrier-free MFMA node kernel: 1 wave = 32 nodes, 4 waves/block (unchanged).
// ---------------------------------------------------------------------------
__global__ __launch_bounds__(256) void node_mfma(
    const float* __restrict__ Qc, const float* __restrict__ Qu,
    const int*   __restrict__ batch,
    const uint32_t* __restrict__ PW3, const uint32_t* __restrict__ PW4,
    const float* __restrict__ b4,
    const float* __restrict__ agg_sum, const int* __restrict__ agg_maxb,
    const int*   __restrict__ offs,
    float* __restrict__ out, int N)
{
    __shared__ float Hl_all[4 * 32 * 34];
    const int w    = threadIdx.x >> 6;
    float* Hl      = Hl_all + w * (32 * 34);
    const int lane = threadIdx.x & 63;
    const int l15  = lane & 15;
    const int l4   = lane >> 4;
    const int n0   = blockIdx.x * 128 + w * 32;
    if (n0 >= N) return;

    f32x4 acc1[2][2];
#pragma unroll
    for (int mt = 0; mt < 2; ++mt)
#pragma unroll
        for (int r = 0; r < 4; ++r) {
            const int nc = min(n0 + mt * 16 + l4 * 4 + r, N - 1);
            const int g  = batch[nc];
#pragma unroll
            for (int nt = 0; nt < 2; ++nt)
                acc1[mt][nt][r] = Qc[(size_t)nc * HIDN + nt * 16 + l15]
                                + Qu[(size_t)g  * HIDN + nt * 16 + l15];
        }

    int   arn[2];
    float ainv[2];
#pragma unroll
    for (int mt = 0; mt < 2; ++mt) {
        arn[mt] = min(n0 + mt * 16 + l15, N - 1);
        const int deg = offs[arn[mt] + 1] - offs[arn[mt]];
        ainv[mt] = (deg > 0) ? 1.0f / (float)deg : 0.0f;
    }

    Frag B3[2][4];
#pragma unroll
    for (int nt = 0; nt < 2; ++nt)
#pragma unroll
        for (int ks = 0; ks < 4; ++ks) {
            const uint4 q = *reinterpret_cast<const uint4*>(
                &PW3[(nt * 16 + l15) * 64 + ks * 16 + l4 * 4]);
            B3[nt][ks].u[0] = q.x; B3[nt][ks].u[1] = q.y;
            B3[nt][ks].u[2] = q.z; B3[nt][ks].u[3] = q.w;
        }

#pragma unroll
    for (int ks = 0; ks < 4; ++ks) {
        Frag A[2];
        if (ks < 2) {
#pragma unroll
            for (int mt = 0; mt < 2; ++mt) {
                const float4* gp = reinterpret_cast<const float4*>(
                    agg_sum + (size_t)arn[mt] * FMSG + ks * 32 + l4 * 8);
                const float4 f0 = gp[0], f1 = gp[1];
                const float s = ainv[mt];
                A[mt].u[0] = packrn(f0.x * s, f0.y * s);
                A[mt].u[1] = packrn(f0.z * s, f0.w * s);
                A[mt].u[2] = packrn(f1.x * s, f1.y * s);
                A[mt].u[3] = packrn(f1.z * s, f1.w * s);
            }
        } else {
#pragma unroll
            for (int mt = 0; mt < 2; ++mt) {
                const uint4* gp = reinterpret_cast<const uint4*>(
                    agg_maxb + (size_t)arn[mt] * FMSG + (ks - 2) * 32 + l4 * 8);
                const uint4 u0 = gp[0], u1 = gp[1];
                A[mt].u[0] = packrn(__uint_as_float(u0.x), __uint_as_float(u0.y));
                A[mt].u[1] = packrn(__uint_as_float(u0.z), __uint_as_float(u0.w));
                A[mt].u[2] = packrn(__uint_as_float(u1.x), __uint_as_float(u1.y));
                A[mt].u[3] = packrn(__uint_as_float(u1.z), __uint_as_float(u1.w));
            }
        }
#pragma unroll
        for (int mt = 0; mt < 2; ++mt)
#pragma unroll
            for (int nt = 0; nt < 2; ++nt)
                acc1[mt][nt] = __builtin_amdgcn_mfma_f32_16x16x32_bf16(
                    A[mt].v, B3[nt][ks].v, acc1[mt][nt], 0, 0, 0);
    }

#pragma unroll
    for (int mt = 0; mt < 2; ++mt)
#pragma unroll
        for (int nt = 0; nt < 2; ++nt)
#pragma unroll
            for (int r = 0; r < 4; ++r) {
                const int rw = mt * 16 + l4 * 4 + r;
                Hl[rw * 34 + nt * 16 + l15] = fmaxf(acc1[mt][nt][r], 0.0f);
            }

    Frag A2[2];
#pragma unroll
    for (int mt = 0; mt < 2; ++mt) {
        const float* hb = &Hl[(mt * 16 + l15) * 34 + l4 * 8];
        const float2 g0 = *reinterpret_cast<const float2*>(hb + 0);
        const float2 g1 = *reinterpret_cast<const float2*>(hb + 2);
        const float2 g2 = *reinterpret_cast<const float2*>(hb + 4);
        const float2 g3 = *reinterpret_cast<const float2*>(hb + 6);
        A2[mt].u[0] = packrn(g0.x, g0.y);
        A2[mt].u[1] = packrn(g1.x, g1.y);
        A2[mt].u[2] = packrn(g2.x, g2.y);
        A2[mt].u[3] = packrn(g3.x, g3.y);
    }

#pragma unroll
    for (int nt = 0; nt < 8; ++nt) {
        Frag B4f;
        const uint4 q = *reinterpret_cast<const uint4*>(
            &PW4[(nt * 16 + l15) * 16 + l4 * 4]);
        B4f.u[0] = q.x; B4f.u[1] = q.y; B4f.u[2] = q.z; B4f.u[3] = q.w;
        const float b4v = b4[nt * 16 + l15];
        f32x4 tacc[2];
#pragma unroll
        for (int mt = 0; mt < 2; ++mt) {
            tacc[mt] = (f32x4){0.f, 0.f, 0.f, 0.f};
            tacc[mt] = __builtin_amdgcn_mfma_f32_16x16x32_bf16(
                A2[mt].v, B4f.v, tacc[mt], 0, 0, 0);
        }
#pragma unroll
        for (int mt = 0; mt < 2; ++mt)
#pragma unroll
            for (int r = 0; r < 4; ++r) {
                const int node = n0 + mt * 16 + l4 * 4 + r;
                if (node < N)
                    out[(size_t)node * FOUT + nt * 16 + l15] =
                        fmaxf(tacc[mt][r] + b4v, 0.0f);
            }
    }
}

// ===========================================================================
extern "C" void kernel_launch(void* const* d_in, const int* in_sizes, int n_in,
                              void* d_out, int out_size, void* d_ws, size_t ws_size,
                              hipStream_t stream)
{
    const float* x     = (const float*)d_in[0];
    const int*   ei    = (const int*)  d_in[1];
    const float* ea    = (const float*)d_in[2];
    const float* u     = (const float*)d_in[3];
    const int*   batch = (const int*)  d_in[4];
    const float* W1    = (const float*)d_in[5];
    const float* b1    = (const float*)d_in[6];
    const float* W2    = (const float*)d_in[7];
    const float* b2    = (const float*)d_in[8];
    const float* W3    = (const float*)d_in[9];
    const float* b3    = (const float*)d_in[10];
    const float* W4    = (const float*)d_in[11];
    const float* b4    = (const float*)d_in[12];
    float* out = (float*)d_out;

    const int N = in_sizes[0] / FN;   // 50000
    const int E = in_sizes[1] / 2;    // 800000
    const int G = in_sizes[3] / FN;   // 64
    const int NT = (E + 63) / 64;     // 64-edge tiles

    char* wp = (char*)d_ws;
    auto take = [&](size_t bytes) -> void* {
        void* r = (void*)wp;
        wp += (bytes + 255) & ~(size_t)255;
        return r;
    };
    float*    agg_sum  = (float*)   take((size_t)N * FMSG * 4);
    int*      agg_maxb = (int*)     take((size_t)N * FMSG * 4);
    char*     zero_end = wp;                       // agg zero span (in prep_tail)
    int*      cnt      = (int*)     take((size_t)N * 4);
    int*      offs     = (int*)     take(((size_t)N + 1) * 4);
    int*      rank     = (int*)     take((size_t)E * 4);
    int4*     re4      = (int4*)    take((size_t)E * 16);
    int2*     ntile    = (int2*)    take((size_t)NT * 8);
    float*    Pa       = (float*)   take((size_t)N * HIDN * 4);
    float*    Pb       = (float*)   take((size_t)N * HIDN * 4);
    float*    Qc       = (float*)   take((size_t)N * HIDN * 4);
    float*    Qu       = (float*)   take((size_t)G * HIDN * 4);
    uint32_t* PW1      = (uint32_t*)take(1024 * 4);
    uint32_t* PW2      = (uint32_t*)take(1024 * 4);
    uint32_t* PW3      = (uint32_t*)take(2048 * 4);
    uint32_t* PW4      = (uint32_t*)take(2048 * 4);
    int*      part     = (int*)     take(64 * 4);
    int*      partx    = (int*)     take(64 * 4);

    const int BZ = 256;                            // agg-zero blocks
    const int NB = (N + 2047) / 2048;              // scan blocks
    const int SB = (E + 255) / 256;                // scatter blocks
    const int TB = (NT + 255) / 256;               // ntile blocks
    const size_t zquads = (size_t)(zero_end - (char*)agg_sum) / 16;

    zero_cnt_kernel<<<(N + 255) / 256, 256, 0, stream>>>(cnt, N);
    hist_kernel    <<<(E + 255) / 256, 256, 0, stream>>>(ei, cnt, rank, E);
    node_pre_kernel<<<(N + 127) / 128, 128, 0, stream>>>(
        x, W1, b1, W3, b3, Pa, Pb, Qc, N);
    prep_tail_kernel<<<1 + BZ, 256, 0, stream>>>(
        u, W1, W2, W3, W4, Qu, PW1, PW2, PW3, PW4,
        (uint4*)agg_sum, zquads, G, BZ);
    scanA_kernel   <<<NB, 256, 0, stream>>>(cnt, part, N);
    scanB_kernel   <<<1, 64, 0, stream>>>(part, partx, offs, NB, N);
    scanC_kernel   <<<NB, 256, 0, stream>>>(cnt, partx, offs, N);
    scatter_ntile_kernel<<<SB + TB, 256, 0, stream>>>(
        ei, offs, rank, re4, ntile, E, N, NT, SB);
    fused_edge_mfma<<<(NT + 1) / 2, 128, 0, stream>>>(
        ea, PW1, PW2, b2, Pa, Pb, re4, offs, ntile, agg_sum, agg_maxb, N, E, NT);
    node_mfma      <<<(N + 127) / 128, 256, 0, stream>>>(
        Qc, Qu, batch, PW3, PW4, b4, agg_sum, agg_maxb, offs, out, N);
}

// Round 12
// 198.384 us; speedup vs baseline: 1.2405x; 1.2405x over previous
//
#include <hip/hip_runtime.h>
#include <hip/hip_bf16.h>
#include <stdint.h>

constexpr int FN   = 64;
constexpr int HIDN = 32;
constexpr int FMSG = 64;
constexpr int FOUT = 128;

using short8 = __attribute__((ext_vector_type(8))) short;
using f32x4  = __attribute__((ext_vector_type(4))) float;

union Frag { short8 v; uint32_t u[4]; };

__device__ __forceinline__ uint32_t packrn(float a, float b) {
    union { __hip_bfloat162 h; uint32_t u; } cv;
    cv.h = __float22bfloat162_rn(make_float2(a, b));   // v_cvt_pk_bf16_f32
    return cv.u;
}
__device__ __forceinline__ float bf16_to_f(uint32_t h16) {
    return __uint_as_float(h16 << 16);
}

__device__ __forceinline__ int node_of(const int* __restrict__ offs, int N, int target) {
    int l = 0, r = N + 1;
    while (l + 1 < r) {
        const int m = (l + r) >> 1;
        if (offs[m] <= target) l = m; else r = m;
    }
    return l;
}

// ---------------------------------------------------------------------------
__global__ __launch_bounds__(256) void zero_cnt_kernel(int* __restrict__ cnt, int N)
{
    const int i = blockIdx.x * 256 + threadIdx.x;
    if (i < N) cnt[i] = 0;
}

// ---------------------------------------------------------------------------
// mega_prep: [0,BH) hist (8 atomics/thread, max ILP)
//          | [BH,BH+BPN) node_pre (coalesced LDS-staged, 4 waves x 64 nodes)
//          | [BH+BPN] pack weights + Qu
//          | [BH+BPN+1, +BZ) agg zero
// One grid so the latency-bound hist waves overlap the BW/VALU filler blocks.
// ---------------------------------------------------------------------------
__global__ __launch_bounds__(256) void mega_prep_kernel(
    const int* __restrict__ ei, int* __restrict__ cnt, int* __restrict__ rank,
    const float* __restrict__ x, const float* __restrict__ u,
    const float* __restrict__ W1, const float* __restrict__ b1,
    const float* __restrict__ W2,
    const float* __restrict__ W3, const float* __restrict__ b3,
    const float* __restrict__ W4,
    float* __restrict__ Pa, float* __restrict__ Pb, float* __restrict__ Qc,
    float* __restrict__ Qu,
    uint32_t* __restrict__ PW1, uint32_t* __restrict__ PW2,
    uint32_t* __restrict__ PW3, uint32_t* __restrict__ PW4,
    uint4* __restrict__ zbase, size_t zquads,
    int E, int N, int G, int BH, int BPN, int BZ)
{
    __shared__ float xs_all[4 * 64 * 33];   // node_pre staging (33.8 KB)
    const int b   = blockIdx.x;
    const int tid = threadIdx.x;

    if (b < BH) {
        // ---- hist: 8 independent atomic-with-return per thread ----
        const int base = (b * 256 + tid) * 8;
        if (base + 8 <= E) {
            const int4 c0 = *reinterpret_cast<const int4*>(ei + E + base);
            const int4 c1 = *reinterpret_cast<const int4*>(ei + E + base + 4);
            int4 r0, r1;
            r0.x = atomicAdd(cnt + c0.x, 1);
            r0.y = atomicAdd(cnt + c0.y, 1);
            r0.z = atomicAdd(cnt + c0.z, 1);
            r0.w = atomicAdd(cnt + c0.w, 1);
            r1.x = atomicAdd(cnt + c1.x, 1);
            r1.y = atomicAdd(cnt + c1.y, 1);
            r1.z = atomicAdd(cnt + c1.z, 1);
            r1.w = atomicAdd(cnt + c1.w, 1);
            *reinterpret_cast<int4*>(rank + base)     = r0;
            *reinterpret_cast<int4*>(rank + base + 4) = r1;
        } else {
            for (int e = base; e < E; ++e) rank[e] = atomicAdd(cnt + ei[E + e], 1);
        }
        return;
    }
    if (b < BH + BPN) {
        // ---- node_pre: per-wave 64 nodes, 2 column-chunks of 32 via LDS ----
        const int w    = tid >> 6;
        const int lane = tid & 63;
        float* xs = xs_all + w * (64 * 33);
        const int nbase = (b - BH) * 256 + w * 64;
        if (nbase >= N) return;

        float a[HIDN], bq[HIDN], cc[HIDN];
#pragma unroll
        for (int j = 0; j < HIDN; ++j) { a[j] = b1[j]; bq[j] = 0.0f; cc[j] = b3[j]; }

#pragma unroll
        for (int c = 0; c < 2; ++c) {
            // stage cols [c*32, c*32+32) of 64 rows; coalesced-ish (8 lines/instr)
#pragma unroll
            for (int i = 0; i < 8; ++i) {
                const int idx = i * 64 + lane;
                const int row = idx >> 3, cq = idx & 7;
                const int nr  = min(nbase + row, N - 1);
                const float4 v = *reinterpret_cast<const float4*>(
                    x + (size_t)nr * FN + c * 32 + cq * 4);
                float* d = xs + row * 33 + cq * 4;
                d[0] = v.x; d[1] = v.y; d[2] = v.z; d[3] = v.w;
            }
            // wave-local: in-order DS pipe, no barrier needed
            const float* xr = xs + lane * 33;
#pragma unroll 2
            for (int k = 0; k < 32; k += 4) {
                const float v0 = xr[k], v1 = xr[k + 1], v2 = xr[k + 2], v3 = xr[k + 3];
                const int kg = c * 32 + k;
                const float* wa = W1 + kg * HIDN;
                const float* wb = W1 + FN * HIDN + kg * HIDN;
                const float* wc = W3 + kg * HIDN;
#pragma unroll
                for (int j = 0; j < HIDN; ++j) {
                    float aj = a[j], bj = bq[j], cj = cc[j];
                    aj = fmaf(v0, wa[j], aj);            bj = fmaf(v0, wb[j], bj);            cj = fmaf(v0, wc[j], cj);
                    aj = fmaf(v1, wa[HIDN + j], aj);     bj = fmaf(v1, wb[HIDN + j], bj);     cj = fmaf(v1, wc[HIDN + j], cj);
                    aj = fmaf(v2, wa[2 * HIDN + j], aj); bj = fmaf(v2, wb[2 * HIDN + j], bj); cj = fmaf(v2, wc[2 * HIDN + j], cj);
                    aj = fmaf(v3, wa[3 * HIDN + j], aj); bj = fmaf(v3, wb[3 * HIDN + j], bj); cj = fmaf(v3, wc[3 * HIDN + j], cj);
                    a[j] = aj; bq[j] = bj; cc[j] = cj;
                }
            }
        }
        const int n = nbase + lane;
        if (n >= N) return;
        float4* pa = reinterpret_cast<float4*>(Pa + (size_t)n * HIDN);
        float4* pb = reinterpret_cast<float4*>(Pb + (size_t)n * HIDN);
        float4* qc = reinterpret_cast<float4*>(Qc + (size_t)n * HIDN);
#pragma unroll
        for (int q = 0; q < HIDN / 4; ++q) {
            pa[q] = make_float4(a[4*q], a[4*q+1], a[4*q+2], a[4*q+3]);
            pb[q] = make_float4(bq[4*q], bq[4*q+1], bq[4*q+2], bq[4*q+3]);
            qc[q] = make_float4(cc[4*q], cc[4*q+1], cc[4*q+2], cc[4*q+3]);
        }
        return;
    }
    if (b == BH + BPN) {
        // ---- pack weights + Qu ----
        const float* WC = W1 + 2 * FN * HIDN;
        for (int i = tid; i < 1024; i += 256) {
            const int j = i >> 5, k2 = i & 31;
            PW1[i] = packrn(WC[(2 * k2) * HIDN + j], WC[(2 * k2 + 1) * HIDN + j]);
        }
        for (int i = tid; i < 1024; i += 256) {
            const int j = i >> 4, k2 = i & 15;
            PW2[i] = packrn(W2[(2 * k2) * FMSG + j], W2[(2 * k2 + 1) * FMSG + j]);
        }
        const float* W3m = W3 + 64 * HIDN;
        for (int i = tid; i < 2048; i += 256) {
            const int j = i >> 6, k2 = i & 63;
            PW3[i] = packrn(W3m[(2 * k2) * HIDN + j], W3m[(2 * k2 + 1) * HIDN + j]);
        }
        for (int i = tid; i < 2048; i += 256) {
            const int j = i >> 4, k2 = i & 15;
            PW4[i] = packrn(W4[(2 * k2) * FOUT + j], W4[(2 * k2 + 1) * FOUT + j]);
        }
        const float* W3u = W3 + 192 * HIDN;
        for (int i = tid; i < G * HIDN; i += 256) {
            const int g = i >> 5, j = i & 31;
            const float* ur = u + (size_t)g * FN;
            float acc = 0.0f;
#pragma unroll 8
            for (int k = 0; k < FN; ++k) acc = fmaf(ur[k], W3u[k * HIDN + j], acc);
            Qu[i] = acc;
        }
        return;
    }
    // ---- zero agg_sum/agg_maxb ----
    const size_t stride = (size_t)BZ * 256;
    const uint4 z = make_uint4(0u, 0u, 0u, 0u);
    for (size_t i = (size_t)(b - BH - BPN - 1) * 256 + tid; i < zquads; i += stride)
        zbase[i] = z;
}

// ---------------------------------------------------------------------------
__global__ __launch_bounds__(256) void scanA_kernel(
    const int* __restrict__ cnt, int* __restrict__ part, int N)
{
    __shared__ int red[256];
    const int tid  = threadIdx.x;
    const int base = blockIdx.x * 2048 + tid * 8;
    int s = 0;
    if (base + 8 <= N) {
        const int4 a = *reinterpret_cast<const int4*>(cnt + base);
        const int4 b = *reinterpret_cast<const int4*>(cnt + base + 4);
        s = a.x + a.y + a.z + a.w + b.x + b.y + b.z + b.w;
    } else {
        for (int i = base; i < min(base + 8, N); ++i) s += cnt[i];
    }
    red[tid] = s;
    __syncthreads();
    for (int d = 128; d > 0; d >>= 1) {
        if (tid < d) red[tid] += red[tid + d];
        __syncthreads();
    }
    if (tid == 0) part[blockIdx.x] = red[0];
}

// scanC with scanB folded in: each block serially prefixes part[0..NB).
__global__ __launch_bounds__(256) void scanC_kernel(
    const int* __restrict__ cnt, const int* __restrict__ part,
    int* __restrict__ offs, int NB, int N, int E)
{
    __shared__ int sb[256];
    const int tid  = threadIdx.x;
    int px = 0;
    for (int i = 0; i < (int)blockIdx.x; ++i) px += part[i];

    const int base = blockIdx.x * 2048 + tid * 8;
    int v[8];
    int tsum = 0;
#pragma unroll
    for (int q = 0; q < 8; ++q) {
        const int i = base + q;
        v[q] = (i < N) ? cnt[i] : 0;
        tsum += v[q];
    }
    sb[tid] = tsum;
    __syncthreads();
    for (int d = 1; d < 256; d <<= 1) {
        const int t = (tid >= d) ? sb[tid - d] : 0;
        __syncthreads();
        sb[tid] += t;
        __syncthreads();
    }
    int run = px + sb[tid] - tsum;
#pragma unroll
    for (int q = 0; q < 8; ++q) {
        const int i = base + q;
        if (i < N) offs[i] = run;
        run += v[q];
    }
    if (blockIdx.x == 0 && tid == 0) offs[N] = E;
}

// ---------------------------------------------------------------------------
// scatter (blocks [0,SB)) + ntile builder (blocks [SB, SB+TB))
// ---------------------------------------------------------------------------
__global__ __launch_bounds__(256) void scatter_ntile_kernel(
    const int* __restrict__ ei, const int* __restrict__ offs,
    const int* __restrict__ rank, int4* __restrict__ re4,
    int2* __restrict__ ntile, int E, int N, int NT, int SB)
{
    const int tid = threadIdx.x;
    if ((int)blockIdx.x < SB) {
        const int e = blockIdx.x * 256 + tid;
        if (e >= E) return;
        const int row = ei[e];
        const int col = ei[E + e];
        const int pos = offs[col] + rank[e];
        re4[pos] = make_int4(row, col, e, 0);
    } else {
        const int t = ((int)blockIdx.x - SB) * 256 + tid;
        if (t >= NT) return;
        const int a = node_of(offs, N, t * 64);
        const int b = node_of(offs, N, min(t * 64 + 63, E - 1));
        ntile[t] = make_int2(a, b);
    }
}

// ---------------------------------------------------------------------------
// Barrier-free MFMA fused edge kernel: 1 wave = 64 sorted edges (unchanged).
// ---------------------------------------------------------------------------
__global__ __launch_bounds__(128) void fused_edge_mfma(
    const float* __restrict__ ea,
    const uint32_t* __restrict__ PW1, const uint32_t* __restrict__ PW2,
    const float* __restrict__ b2,
    const float* __restrict__ Pa, const float* __restrict__ Pb,
    const int4* __restrict__ re4, const int* __restrict__ offs,
    const int2* __restrict__ ntile,
    float* __restrict__ agg_sum, int* __restrict__ agg_maxb,
    int N, int E, int NT)
{
    __shared__ uint32_t smem_all[2 * 64 * 34];
    const int w    = threadIdx.x >> 6;
    const int t    = blockIdx.x * 2 + w;
    if (t >= NT) return;
    uint32_t* smem = smem_all + w * (64 * 34);
    const int lane = threadIdx.x & 63;
    const int l15  = lane & 15;
    const int l4   = lane >> 4;
    const int e0   = t * 64;
    const int e1   = min(e0 + 64, E);
    const int2 nrange = ntile[t];

    const int p = e0 + lane;
    const int4 rce = re4[min(p, E - 1)];
    {
        const float2* pa = reinterpret_cast<const float2*>(Pa + (size_t)rce.x * HIDN);
        const float2* pb = reinterpret_cast<const float2*>(Pb + (size_t)rce.y * HIDN);
        float2* dst = reinterpret_cast<float2*>(&smem[lane * 34]);
#pragma unroll
        for (int q = 0; q < 16; ++q) {
            const float2 a = pa[q], b = pb[q];
            dst[q] = make_float2(a.x + b.x, a.y + b.y);
        }
    }

    Frag B1[2][2];
#pragma unroll
    for (int nt = 0; nt < 2; ++nt)
#pragma unroll
        for (int ks = 0; ks < 2; ++ks) {
            const uint4 q = *reinterpret_cast<const uint4*>(
                &PW1[(nt * 16 + l15) * 32 + ks * 16 + l4 * 4]);
            B1[nt][ks].u[0] = q.x; B1[nt][ks].u[1] = q.y;
            B1[nt][ks].u[2] = q.z; B1[nt][ks].u[3] = q.w;
        }
    Frag B2f[4];
#pragma unroll
    for (int nt = 0; nt < 4; ++nt) {
        const uint4 q = *reinterpret_cast<const uint4*>(
            &PW2[(nt * 16 + l15) * 16 + l4 * 4]);
        B2f[nt].u[0] = q.x; B2f[nt].u[1] = q.y;
        B2f[nt].u[2] = q.z; B2f[nt].u[3] = q.w;
    }

    Frag A1[4][2];
#pragma unroll
    for (int mt = 0; mt < 4; ++mt) {
        const int eix = __shfl(rce.z, mt * 16 + l15, 64);
        const float* rp = ea + (size_t)eix * FN;
#pragma unroll
        for (int ks = 0; ks < 2; ++ks) {
            const float4* gp = reinterpret_cast<const float4*>(rp + ks * 32 + l4 * 8);
            const float4 f0 = gp[0], f1 = gp[1];
            A1[mt][ks].u[0] = packrn(f0.x, f0.y);
            A1[mt][ks].u[1] = packrn(f0.z, f0.w);
            A1[mt][ks].u[2] = packrn(f1.x, f1.y);
            A1[mt][ks].u[3] = packrn(f1.z, f1.w);
        }
    }

    f32x4 acc1[4][2];
    const float* Pl = reinterpret_cast<const float*>(smem);
#pragma unroll
    for (int mt = 0; mt < 4; ++mt)
#pragma unroll
        for (int nt = 0; nt < 2; ++nt)
#pragma unroll
            for (int r = 0; r < 4; ++r) {
                const int et = mt * 16 + l4 * 4 + r;
                acc1[mt][nt][r] = Pl[et * 34 + nt * 16 + l15];
            }
#pragma unroll
    for (int mt = 0; mt < 4; ++mt)
#pragma unroll
        for (int nt = 0; nt < 2; ++nt)
#pragma unroll
            for (int ks = 0; ks < 2; ++ks)
                acc1[mt][nt] = __builtin_amdgcn_mfma_f32_16x16x32_bf16(
                    A1[mt][ks].v, B1[nt][ks].v, acc1[mt][nt], 0, 0, 0);

    float* Hl = reinterpret_cast<float*>(smem);
#pragma unroll
    for (int mt = 0; mt < 4; ++mt)
#pragma unroll
        for (int nt = 0; nt < 2; ++nt)
#pragma unroll
            for (int r = 0; r < 4; ++r) {
                const int et = mt * 16 + l4 * 4 + r;
                Hl[et * 34 + nt * 16 + l15] = fmaxf(acc1[mt][nt][r], 0.0f);
            }

    Frag A2[4];
#pragma unroll
    for (int mt = 0; mt < 4; ++mt) {
        const float* hb = &Hl[(mt * 16 + l15) * 34 + l4 * 8];
        const float2 g0 = *reinterpret_cast<const float2*>(hb + 0);
        const float2 g1 = *reinterpret_cast<const float2*>(hb + 2);
        const float2 g2 = *reinterpret_cast<const float2*>(hb + 4);
        const float2 g3 = *reinterpret_cast<const float2*>(hb + 6);
        A2[mt].u[0] = packrn(g0.x, g0.y);
        A2[mt].u[1] = packrn(g1.x, g1.y);
        A2[mt].u[2] = packrn(g2.x, g2.y);
        A2[mt].u[3] = packrn(g3.x, g3.y);
    }

#pragma unroll
    for (int nt = 0; nt < 4; ++nt) {
        const float b2v = b2[nt * 16 + l15];
        f32x4 a2c[4];
#pragma unroll
        for (int mt = 0; mt < 4; ++mt) {
            a2c[mt] = (f32x4){0.f, 0.f, 0.f, 0.f};
            a2c[mt] = __builtin_amdgcn_mfma_f32_16x16x32_bf16(
                A2[mt].v, B2f[nt].v, a2c[mt], 0, 0, 0);
        }
        const int j = nt * 16 + l15;
#pragma unroll
        for (int mt = 0; mt < 4; ++mt)
#pragma unroll
            for (int rp2 = 0; rp2 < 2; ++rp2) {
                const int q2 = mt * 8 + l4 * 2 + rp2;
                const float v0 = fmaxf(a2c[mt][rp2 * 2]     + b2v, 0.0f);
                const float v1 = fmaxf(a2c[mt][rp2 * 2 + 1] + b2v, 0.0f);
                smem[q2 * 64 + (j ^ (((q2 >> 1) & 1) << 4))] = packrn(v0, v1);
            }
    }

    const int n0 = nrange.x, n1 = nrange.y;
    for (int n = n0; n <= n1; ++n) {
        const int s0 = offs[n], t0 = offs[n + 1];
        const int sl = max(s0, e0) - e0, tl = min(t0, e1) - e0;
        float sum = 0.0f, mx = 0.0f;
        int q = sl;
        if (q < tl && (q & 1)) {
            const int q2 = q >> 1;
            const uint32_t wv = smem[q2 * 64 + (lane ^ (((q2 >> 1) & 1) << 4))];
            const float v = bf16_to_f(wv >> 16);
            sum += v; mx = fmaxf(mx, v); ++q;
        }
        for (; q + 1 < tl; q += 2) {
            const int q2 = q >> 1;
            const uint32_t wv = smem[q2 * 64 + (lane ^ (((q2 >> 1) & 1) << 4))];
            const float v0 = bf16_to_f(wv & 0xffffu), v1 = bf16_to_f(wv >> 16);
            sum += v0 + v1; mx = fmaxf(mx, fmaxf(v0, v1));
        }
        if (q < tl) {
            const int q2 = q >> 1;
            const uint32_t wv = smem[q2 * 64 + (lane ^ (((q2 >> 1) & 1) << 4))];
            const float v = bf16_to_f(wv & 0xffffu);
            sum += v; mx = fmaxf(mx, v);
        }
        float* sp = agg_sum  + (size_t)n * FMSG + lane;
        int*   mp = agg_maxb + (size_t)n * FMSG + lane;
        if (s0 >= e0 && t0 <= e1) {
            *sp = sum;
            *mp = __float_as_int(mx);
        } else {
            unsafeAtomicAdd(sp, sum);
            atomicMax(mp, __float_as_int(mx));
        }
    }
}

// ---------------------------------------------------------------------------
// Barrier-free MFMA node kernel: 1 wave = 32 nodes, 4 waves/block (unchanged).
// ---------------------------------------------------------------------------
__global__ __launch_bounds__(256) void node_mfma(
    const float* __restrict__ Qc, const float* __restrict__ Qu,
    const int*   __restrict__ batch,
    const uint32_t* __restrict__ PW3, const uint32_t* __restrict__ PW4,
    const float* __restrict__ b4,
    const float* __restrict__ agg_sum, const int* __restrict__ agg_maxb,
    const int*   __restrict__ offs,
    float* __restrict__ out, int N)
{
    __shared__ float Hl_all[4 * 32 * 34];
    const int w    = threadIdx.x >> 6;
    float* Hl      = Hl_all + w * (32 * 34);
    const int lane = threadIdx.x & 63;
    const int l15  = lane & 15;
    const int l4   = lane >> 4;
    const int n0   = blockIdx.x * 128 + w * 32;
    if (n0 >= N) return;

    f32x4 acc1[2][2];
#pragma unroll
    for (int mt = 0; mt < 2; ++mt)
#pragma unroll
        for (int r = 0; r < 4; ++r) {
            const int nc = min(n0 + mt * 16 + l4 * 4 + r, N - 1);
            const int g  = batch[nc];
#pragma unroll
            for (int nt = 0; nt < 2; ++nt)
                acc1[mt][nt][r] = Qc[(size_t)nc * HIDN + nt * 16 + l15]
                                + Qu[(size_t)g  * HIDN + nt * 16 + l15];
        }

    int   arn[2];
    float ainv[2];
#pragma unroll
    for (int mt = 0; mt < 2; ++mt) {
        arn[mt] = min(n0 + mt * 16 + l15, N - 1);
        const int deg = offs[arn[mt] + 1] - offs[arn[mt]];
        ainv[mt] = (deg > 0) ? 1.0f / (float)deg : 0.0f;
    }

    Frag B3[2][4];
#pragma unroll
    for (int nt = 0; nt < 2; ++nt)
#pragma unroll
        for (int ks = 0; ks < 4; ++ks) {
            const uint4 q = *reinterpret_cast<const uint4*>(
                &PW3[(nt * 16 + l15) * 64 + ks * 16 + l4 * 4]);
            B3[nt][ks].u[0] = q.x; B3[nt][ks].u[1] = q.y;
            B3[nt][ks].u[2] = q.z; B3[nt][ks].u[3] = q.w;
        }

#pragma unroll
    for (int ks = 0; ks < 4; ++ks) {
        Frag A[2];
        if (ks < 2) {
#pragma unroll
            for (int mt = 0; mt < 2; ++mt) {
                const float4* gp = reinterpret_cast<const float4*>(
                    agg_sum + (size_t)arn[mt] * FMSG + ks * 32 + l4 * 8);
                const float4 f0 = gp[0], f1 = gp[1];
                const float s = ainv[mt];
                A[mt].u[0] = packrn(f0.x * s, f0.y * s);
                A[mt].u[1] = packrn(f0.z * s, f0.w * s);
                A[mt].u[2] = packrn(f1.x * s, f1.y * s);
                A[mt].u[3] = packrn(f1.z * s, f1.w * s);
            }
        } else {
#pragma unroll
            for (int mt = 0; mt < 2; ++mt) {
                const uint4* gp = reinterpret_cast<const uint4*>(
                    agg_maxb + (size_t)arn[mt] * FMSG + (ks - 2) * 32 + l4 * 8);
                const uint4 u0 = gp[0], u1 = gp[1];
                A[mt].u[0] = packrn(__uint_as_float(u0.x), __uint_as_float(u0.y));
                A[mt].u[1] = packrn(__uint_as_float(u0.z), __uint_as_float(u0.w));
                A[mt].u[2] = packrn(__uint_as_float(u1.x), __uint_as_float(u1.y));
                A[mt].u[3] = packrn(__uint_as_float(u1.z), __uint_as_float(u1.w));
            }
        }
#pragma unroll
        for (int mt = 0; mt < 2; ++mt)
#pragma unroll
            for (int nt = 0; nt < 2; ++nt)
                acc1[mt][nt] = __builtin_amdgcn_mfma_f32_16x16x32_bf16(
                    A[mt].v, B3[nt][ks].v, acc1[mt][nt], 0, 0, 0);
    }

#pragma unroll
    for (int mt = 0; mt < 2; ++mt)
#pragma unroll
        for (int nt = 0; nt < 2; ++nt)
#pragma unroll
            for (int r = 0; r < 4; ++r) {
                const int rw = mt * 16 + l4 * 4 + r;
                Hl[rw * 34 + nt * 16 + l15] = fmaxf(acc1[mt][nt][r], 0.0f);
            }

    Frag A2[2];
#pragma unroll
    for (int mt = 0; mt < 2; ++mt) {
        const float* hb = &Hl[(mt * 16 + l15) * 34 + l4 * 8];
        const float2 g0 = *reinterpret_cast<const float2*>(hb + 0);
        const float2 g1 = *reinterpret_cast<const float2*>(hb + 2);
        const float2 g2 = *reinterpret_cast<const float2*>(hb + 4);
        const float2 g3 = *reinterpret_cast<const float2*>(hb + 6);
        A2[mt].u[0] = packrn(g0.x, g0.y);
        A2[mt].u[1] = packrn(g1.x, g1.y);
        A2[mt].u[2] = packrn(g2.x, g2.y);
        A2[mt].u[3] = packrn(g3.x, g3.y);
    }

#pragma unroll
    for (int nt = 0; nt < 8; ++nt) {
        Frag B4f;
        const uint4 q = *reinterpret_cast<const uint4*>(
            &PW4[(nt * 16 + l15) * 16 + l4 * 4]);
        B4f.u[0] = q.x; B4f.u[1] = q.y; B4f.u[2] = q.z; B4f.u[3] = q.w;
        const float b4v = b4[nt * 16 + l15];
        f32x4 tacc[2];
#pragma unroll
        for (int mt = 0; mt < 2; ++mt) {
            tacc[mt] = (f32x4){0.f, 0.f, 0.f, 0.f};
            tacc[mt] = __builtin_amdgcn_mfma_f32_16x16x32_bf16(
                A2[mt].v, B4f.v, tacc[mt], 0, 0, 0);
        }
#pragma unroll
        for (int mt = 0; mt < 2; ++mt)
#pragma unroll
            for (int r = 0; r < 4; ++r) {
                const int node = n0 + mt * 16 + l4 * 4 + r;
                if (node < N)
                    out[(size_t)node * FOUT + nt * 16 + l15] =
                        fmaxf(tacc[mt][r] + b4v, 0.0f);
            }
    }
}

// ===========================================================================
extern "C" void kernel_launch(void* const* d_in, const int* in_sizes, int n_in,
                              void* d_out, int out_size, void* d_ws, size_t ws_size,
                              hipStream_t stream)
{
    const float* x     = (const float*)d_in[0];
    const int*   ei    = (const int*)  d_in[1];
    const float* ea    = (const float*)d_in[2];
    const float* u     = (const float*)d_in[3];
    const int*   batch = (const int*)  d_in[4];
    const float* W1    = (const float*)d_in[5];
    const float* b1    = (const float*)d_in[6];
    const float* W2    = (const float*)d_in[7];
    const float* b2    = (const float*)d_in[8];
    const float* W3    = (const float*)d_in[9];
    const float* b3    = (const float*)d_in[10];
    const float* W4    = (const float*)d_in[11];
    const float* b4    = (const float*)d_in[12];
    float* out = (float*)d_out;

    const int N = in_sizes[0] / FN;   // 50000
    const int E = in_sizes[1] / 2;    // 800000
    const int G = in_sizes[3] / FN;   // 64
    const int NT = (E + 63) / 64;     // 64-edge tiles

    char* wp = (char*)d_ws;
    auto take = [&](size_t bytes) -> void* {
        void* r = (void*)wp;
        wp += (bytes + 255) & ~(size_t)255;
        return r;
    };
    float*    agg_sum  = (float*)   take((size_t)N * FMSG * 4);
    int*      agg_maxb = (int*)     take((size_t)N * FMSG * 4);
    char*     zero_end = wp;                       // agg zero span (in mega_prep)
    int*      cnt      = (int*)     take((size_t)N * 4);
    int*      offs     = (int*)     take(((size_t)N + 1) * 4);
    int*      rank     = (int*)     take((size_t)E * 4);
    int4*     re4      = (int4*)    take((size_t)E * 16);
    int2*     ntile    = (int2*)    take((size_t)NT * 8);
    float*    Pa       = (float*)   take((size_t)N * HIDN * 4);
    float*    Pb       = (float*)   take((size_t)N * HIDN * 4);
    float*    Qc       = (float*)   take((size_t)N * HIDN * 4);
    float*    Qu       = (float*)   take((size_t)G * HIDN * 4);
    uint32_t* PW1      = (uint32_t*)take(1024 * 4);
    uint32_t* PW2      = (uint32_t*)take(1024 * 4);
    uint32_t* PW3      = (uint32_t*)take(2048 * 4);
    uint32_t* PW4      = (uint32_t*)take(2048 * 4);
    int*      part     = (int*)     take(64 * 4);

    const int BH  = (E + 2047) / 2048;             // hist blocks (8 edges/thread)
    const int BPN = (N + 255) / 256;               // node_pre blocks (256 nodes each)
    const int BZ  = 256;                           // agg-zero blocks
    const int NB  = (N + 2047) / 2048;             // scan blocks
    const int SB  = (E + 255) / 256;               // scatter blocks
    const int TB  = (NT + 255) / 256;              // ntile blocks
    const size_t zquads = (size_t)(zero_end - (char*)agg_sum) / 16;

    zero_cnt_kernel<<<(N + 255) / 256, 256, 0, stream>>>(cnt, N);
    mega_prep_kernel<<<BH + BPN + 1 + BZ, 256, 0, stream>>>(
        ei, cnt, rank, x, u, W1, b1, W2, W3, b3, W4,
        Pa, Pb, Qc, Qu, PW1, PW2, PW3, PW4,
        (uint4*)agg_sum, zquads, E, N, G, BH, BPN, BZ);
    scanA_kernel   <<<NB, 256, 0, stream>>>(cnt, part, N);
    scanC_kernel   <<<NB, 256, 0, stream>>>(cnt, part, offs, NB, N, E);
    scatter_ntile_kernel<<<SB + TB, 256, 0, stream>>>(
        ei, offs, rank, re4, ntile, E, N, NT, SB);
    fused_edge_mfma<<<(NT + 1) / 2, 128, 0, stream>>>(
        ea, PW1, PW2, b2, Pa, Pb, re4, offs, ntile, agg_sum, agg_maxb, N, E, NT);
    node_mfma      <<<(N + 127) / 128, 256, 0, stream>>>(
        Qc, Qu, batch, PW3, PW4, b4, agg_sum, agg_maxb, offs, out, N);
}

// Round 13
// 197.597 us; speedup vs baseline: 1.2454x; 1.0040x over previous
//
#include <hip/hip_runtime.h>
#include <hip/hip_bf16.h>
#include <stdint.h>

constexpr int FN   = 64;
constexpr int HIDN = 32;
constexpr int FMSG = 64;
constexpr int FOUT = 128;

using short8 = __attribute__((ext_vector_type(8))) short;
using f32x4  = __attribute__((ext_vector_type(4))) float;

union Frag { short8 v; uint32_t u[4]; };

__device__ __forceinline__ uint32_t packrn(float a, float b) {
    union { __hip_bfloat162 h; uint32_t u; } cv;
    cv.h = __float22bfloat162_rn(make_float2(a, b));   // v_cvt_pk_bf16_f32
    return cv.u;
}
__device__ __forceinline__ float bf16_to_f(uint32_t h16) {
    return __uint_as_float(h16 << 16);
}

__device__ __forceinline__ int node_of(const int* __restrict__ offs, int N, int target) {
    int l = 0, r = N + 1;
    while (l + 1 < r) {
        const int m = (l + r) >> 1;
        if (offs[m] <= target) l = m; else r = m;
    }
    return l;
}

// ---------------------------------------------------------------------------
__global__ __launch_bounds__(256) void zero_cnt_kernel(int* __restrict__ cnt, int N)
{
    const int i = blockIdx.x * 256 + threadIdx.x;
    if (i < N) cnt[i] = 0;
}

// ---------------------------------------------------------------------------
// mega_prep: [0,BH) hist (8 atomics/thread) | [BH,BH+BPN) node_pre
//          | [BH+BPN] pack (identity-extended) + Qu | [+1, +BZ) agg zero
// ---------------------------------------------------------------------------
__global__ __launch_bounds__(256) void mega_prep_kernel(
    const int* __restrict__ ei, int* __restrict__ cnt, int* __restrict__ rank,
    const float* __restrict__ x, const float* __restrict__ u,
    const float* __restrict__ W1, const float* __restrict__ b1,
    const float* __restrict__ W2,
    const float* __restrict__ W3, const float* __restrict__ b3,
    const float* __restrict__ W4,
    float* __restrict__ Pa, float* __restrict__ Pb, float* __restrict__ Qc,
    float* __restrict__ Qu,
    uint32_t* __restrict__ PW1, uint32_t* __restrict__ PW2,
    uint32_t* __restrict__ PW3, uint32_t* __restrict__ PW4,
    uint4* __restrict__ zbase, size_t zquads,
    int E, int N, int G, int BH, int BPN, int BZ)
{
    __shared__ float xs_all[4 * 64 * 33];
    const int b   = blockIdx.x;
    const int tid = threadIdx.x;

    if (b < BH) {
        const int base = (b * 256 + tid) * 8;
        if (base + 8 <= E) {
            const int4 c0 = *reinterpret_cast<const int4*>(ei + E + base);
            const int4 c1 = *reinterpret_cast<const int4*>(ei + E + base + 4);
            int4 r0, r1;
            r0.x = atomicAdd(cnt + c0.x, 1);
            r0.y = atomicAdd(cnt + c0.y, 1);
            r0.z = atomicAdd(cnt + c0.z, 1);
            r0.w = atomicAdd(cnt + c0.w, 1);
            r1.x = atomicAdd(cnt + c1.x, 1);
            r1.y = atomicAdd(cnt + c1.y, 1);
            r1.z = atomicAdd(cnt + c1.z, 1);
            r1.w = atomicAdd(cnt + c1.w, 1);
            *reinterpret_cast<int4*>(rank + base)     = r0;
            *reinterpret_cast<int4*>(rank + base + 4) = r1;
        } else {
            for (int e = base; e < E; ++e) rank[e] = atomicAdd(cnt + ei[E + e], 1);
        }
        return;
    }
    if (b < BH + BPN) {
        const int w    = tid >> 6;
        const int lane = tid & 63;
        float* xs = xs_all + w * (64 * 33);
        const int nbase = (b - BH) * 256 + w * 64;
        if (nbase >= N) return;

        float a[HIDN], bq[HIDN], cc[HIDN];
#pragma unroll
        for (int j = 0; j < HIDN; ++j) { a[j] = b1[j]; bq[j] = 0.0f; cc[j] = b3[j]; }

#pragma unroll
        for (int c = 0; c < 2; ++c) {
#pragma unroll
            for (int i = 0; i < 8; ++i) {
                const int idx = i * 64 + lane;
                const int row = idx >> 3, cq = idx & 7;
                const int nr  = min(nbase + row, N - 1);
                const float4 v = *reinterpret_cast<const float4*>(
                    x + (size_t)nr * FN + c * 32 + cq * 4);
                float* d = xs + row * 33 + cq * 4;
                d[0] = v.x; d[1] = v.y; d[2] = v.z; d[3] = v.w;
            }
            const float* xr = xs + lane * 33;
#pragma unroll 2
            for (int k = 0; k < 32; k += 4) {
                const float v0 = xr[k], v1 = xr[k + 1], v2 = xr[k + 2], v3 = xr[k + 3];
                const int kg = c * 32 + k;
                const float* wa = W1 + kg * HIDN;
                const float* wb = W1 + FN * HIDN + kg * HIDN;
                const float* wc = W3 + kg * HIDN;
#pragma unroll
                for (int j = 0; j < HIDN; ++j) {
                    float aj = a[j], bj = bq[j], cj = cc[j];
                    aj = fmaf(v0, wa[j], aj);            bj = fmaf(v0, wb[j], bj);            cj = fmaf(v0, wc[j], cj);
                    aj = fmaf(v1, wa[HIDN + j], aj);     bj = fmaf(v1, wb[HIDN + j], bj);     cj = fmaf(v1, wc[HIDN + j], cj);
                    aj = fmaf(v2, wa[2 * HIDN + j], aj); bj = fmaf(v2, wb[2 * HIDN + j], bj); cj = fmaf(v2, wc[2 * HIDN + j], cj);
                    aj = fmaf(v3, wa[3 * HIDN + j], aj); bj = fmaf(v3, wb[3 * HIDN + j], bj); cj = fmaf(v3, wc[3 * HIDN + j], cj);
                    a[j] = aj; bq[j] = bj; cc[j] = cj;
                }
            }
        }
        const int n = nbase + lane;
        if (n >= N) return;
        float4* pa = reinterpret_cast<float4*>(Pa + (size_t)n * HIDN);
        float4* pb = reinterpret_cast<float4*>(Pb + (size_t)n * HIDN);
        float4* qc = reinterpret_cast<float4*>(Qc + (size_t)n * HIDN);
#pragma unroll
        for (int q = 0; q < HIDN / 4; ++q) {
            pa[q] = make_float4(a[4*q], a[4*q+1], a[4*q+2], a[4*q+3]);
            pb[q] = make_float4(bq[4*q], bq[4*q+1], bq[4*q+2], bq[4*q+3]);
            qc[q] = make_float4(cc[4*q], cc[4*q+1], cc[4*q+2], cc[4*q+3]);
        }
        return;
    }
    if (b == BH + BPN) {
        // ---- pack weights (identity-extended) + Qu ----
        const float* WC = W1 + 2 * FN * HIDN;
        for (int i = tid; i < 2048; i += 256) {          // PW1X[j<32][k2<64]
            const int j = i >> 6, k2 = i & 63;
            uint32_t v;
            if (k2 < 32) {
                v = packrn(WC[(2 * k2) * HIDN + j], WC[(2 * k2 + 1) * HIDN + j]);
            } else if (k2 < 48) {
                const int r0 = 2 * (k2 - 32);
                v = packrn(r0 == j ? 1.0f : 0.0f, r0 + 1 == j ? 1.0f : 0.0f);
            } else {
                const int r0 = 2 * (k2 - 48);
                v = packrn(r0 == j ? 1.0f : 0.0f, r0 + 1 == j ? 1.0f : 0.0f);
            }
            PW1[i] = v;
        }
        for (int i = tid; i < 1024; i += 256) {          // PW2[j<64][k2<16]
            const int j = i >> 4, k2 = i & 15;
            PW2[i] = packrn(W2[(2 * k2) * FMSG + j], W2[(2 * k2 + 1) * FMSG + j]);
        }
        const float* W3m = W3 + 64 * HIDN;               // rows 64..191 (mean|max)
        for (int i = tid; i < 3072; i += 256) {          // PW3X[j<32][k2<96]
            const int j = i / 96, k2 = i - j * 96;
            uint32_t v;
            if (k2 < 64) {
                v = packrn(W3m[(2 * k2) * HIDN + j], W3m[(2 * k2 + 1) * HIDN + j]);
            } else if (k2 < 80) {
                const int r0 = 2 * (k2 - 64);
                v = packrn(r0 == j ? 1.0f : 0.0f, r0 + 1 == j ? 1.0f : 0.0f);
            } else {
                const int r0 = 2 * (k2 - 80);
                v = packrn(r0 == j ? 1.0f : 0.0f, r0 + 1 == j ? 1.0f : 0.0f);
            }
            PW3[i] = v;
        }
        for (int i = tid; i < 2048; i += 256) {          // PW4[j<128][k2<16]
            const int j = i >> 4, k2 = i & 15;
            PW4[i] = packrn(W4[(2 * k2) * FOUT + j], W4[(2 * k2 + 1) * FOUT + j]);
        }
        const float* W3u = W3 + 192 * HIDN;
        for (int i = tid; i < G * HIDN; i += 256) {
            const int g = i >> 5, j = i & 31;
            const float* ur = u + (size_t)g * FN;
            float acc = 0.0f;
#pragma unroll 8
            for (int k = 0; k < FN; ++k) acc = fmaf(ur[k], W3u[k * HIDN + j], acc);
            Qu[i] = acc;
        }
        return;
    }
    const size_t stride = (size_t)BZ * 256;
    const uint4 z = make_uint4(0u, 0u, 0u, 0u);
    for (size_t i = (size_t)(b - BH - BPN - 1) * 256 + tid; i < zquads; i += stride)
        zbase[i] = z;
}

// ---------------------------------------------------------------------------
__global__ __launch_bounds__(256) void scanA_kernel(
    const int* __restrict__ cnt, int* __restrict__ part, int N)
{
    __shared__ int red[256];
    const int tid  = threadIdx.x;
    const int base = blockIdx.x * 2048 + tid * 8;
    int s = 0;
    if (base + 8 <= N) {
        const int4 a = *reinterpret_cast<const int4*>(cnt + base);
        const int4 b = *reinterpret_cast<const int4*>(cnt + base + 4);
        s = a.x + a.y + a.z + a.w + b.x + b.y + b.z + b.w;
    } else {
        for (int i = base; i < min(base + 8, N); ++i) s += cnt[i];
    }
    red[tid] = s;
    __syncthreads();
    for (int d = 128; d > 0; d >>= 1) {
        if (tid < d) red[tid] += red[tid + d];
        __syncthreads();
    }
    if (tid == 0) part[blockIdx.x] = red[0];
}

__global__ __launch_bounds__(256) void scanC_kernel(
    const int* __restrict__ cnt, const int* __restrict__ part,
    int* __restrict__ offs, int NB, int N, int E)
{
    __shared__ int sb[256];
    const int tid  = threadIdx.x;
    int px = 0;
    for (int i = 0; i < (int)blockIdx.x; ++i) px += part[i];

    const int base = blockIdx.x * 2048 + tid * 8;
    int v[8];
    int tsum = 0;
#pragma unroll
    for (int q = 0; q < 8; ++q) {
        const int i = base + q;
        v[q] = (i < N) ? cnt[i] : 0;
        tsum += v[q];
    }
    sb[tid] = tsum;
    __syncthreads();
    for (int d = 1; d < 256; d <<= 1) {
        const int t = (tid >= d) ? sb[tid - d] : 0;
        __syncthreads();
        sb[tid] += t;
        __syncthreads();
    }
    int run = px + sb[tid] - tsum;
#pragma unroll
    for (int q = 0; q < 8; ++q) {
        const int i = base + q;
        if (i < N) offs[i] = run;
        run += v[q];
    }
    if (blockIdx.x == 0 && tid == 0) offs[N] = E;
}

// ---------------------------------------------------------------------------
__global__ __launch_bounds__(256) void scatter_ntile_kernel(
    const int* __restrict__ ei, const int* __restrict__ offs,
    const int* __restrict__ rank, int4* __restrict__ re4,
    int2* __restrict__ ntile, int E, int N, int NT, int SB)
{
    const int tid = threadIdx.x;
    if ((int)blockIdx.x < SB) {
        const int e = blockIdx.x * 256 + tid;
        if (e >= E) return;
        const int row = ei[e];
        const int col = ei[E + e];
        const int pos = offs[col] + rank[e];
        re4[pos] = make_int4(row, col, e, 0);
    } else {
        const int t = ((int)blockIdx.x - SB) * 256 + tid;
        if (t >= NT) return;
        const int a = node_of(offs, N, t * 64);
        const int b = node_of(offs, N, min(t * 64 + 63, E - 1));
        ntile[t] = make_int2(a, b);
    }
}

// ---------------------------------------------------------------------------
// Barrier-free MFMA fused edge kernel, identity-extended GEMM1 (K=128):
//   h = relu( [ea | Pa[row] | Pb[col]] @ [WC; I; I] ),  no Ppair LDS staging.
// ---------------------------------------------------------------------------
__global__ __launch_bounds__(128) void fused_edge_mfma(
    const float* __restrict__ ea,
    const uint32_t* __restrict__ PW1, const uint32_t* __restrict__ PW2,
    const float* __restrict__ b2,
    const float* __restrict__ Pa, const float* __restrict__ Pb,
    const int4* __restrict__ re4, const int* __restrict__ offs,
    const int2* __restrict__ ntile,
    float* __restrict__ agg_sum, int* __restrict__ agg_maxb,
    int N, int E, int NT)
{
    __shared__ uint32_t smem_all[2 * 64 * 34];
    const int w    = threadIdx.x >> 6;
    const int t    = blockIdx.x * 2 + w;
    if (t >= NT) return;
    uint32_t* smem = smem_all + w * (64 * 34);
    const int lane = threadIdx.x & 63;
    const int l15  = lane & 15;
    const int l4   = lane >> 4;
    const int e0   = t * 64;
    const int e1   = min(e0 + 64, E);
    const int2 nrange = ntile[t];

    const int p = e0 + lane;
    const int4 rce = re4[min(p, E - 1)];

    // per-mt row indices for A gathers
    int er[4], rr[4], cr[4];
#pragma unroll
    for (int mt = 0; mt < 4; ++mt) {
        er[mt] = __shfl(rce.z, mt * 16 + l15, 64);
        rr[mt] = __shfl(rce.x, mt * 16 + l15, 64);
        cr[mt] = __shfl(rce.y, mt * 16 + l15, 64);
    }

    // ---- GEMM1 over K=128: ks 0,1 = ea; ks 2 = Pa (I); ks 3 = Pb (I) ----
    f32x4 acc1[4][2];
#pragma unroll
    for (int mt = 0; mt < 4; ++mt)
#pragma unroll
        for (int nt = 0; nt < 2; ++nt)
            acc1[mt][nt] = (f32x4){0.f, 0.f, 0.f, 0.f};

#pragma unroll
    for (int ks = 0; ks < 4; ++ks) {
        Frag Bk[2];
#pragma unroll
        for (int nt = 0; nt < 2; ++nt) {
            const uint4 q = *reinterpret_cast<const uint4*>(
                &PW1[(nt * 16 + l15) * 64 + ks * 16 + l4 * 4]);
            Bk[nt].u[0] = q.x; Bk[nt].u[1] = q.y;
            Bk[nt].u[2] = q.z; Bk[nt].u[3] = q.w;
        }
        Frag A[4];
#pragma unroll
        for (int mt = 0; mt < 4; ++mt) {
            const float* src;
            if (ks < 2)       src = ea + (size_t)er[mt] * FN + ks * 32 + l4 * 8;
            else if (ks == 2) src = Pa + (size_t)rr[mt] * HIDN + l4 * 8;
            else              src = Pb + (size_t)cr[mt] * HIDN + l4 * 8;
            const float4 f0 = *reinterpret_cast<const float4*>(src);
            const float4 f1 = *reinterpret_cast<const float4*>(src + 4);
            A[mt].u[0] = packrn(f0.x, f0.y);
            A[mt].u[1] = packrn(f0.z, f0.w);
            A[mt].u[2] = packrn(f1.x, f1.y);
            A[mt].u[3] = packrn(f1.z, f1.w);
        }
#pragma unroll
        for (int mt = 0; mt < 4; ++mt)
#pragma unroll
            for (int nt = 0; nt < 2; ++nt)
                acc1[mt][nt] = __builtin_amdgcn_mfma_f32_16x16x32_bf16(
                    A[mt].v, Bk[nt].v, acc1[mt][nt], 0, 0, 0);
    }

    // ---- h -> LDS (wave-local transpose), relu ----
    float* Hl = reinterpret_cast<float*>(smem);
#pragma unroll
    for (int mt = 0; mt < 4; ++mt)
#pragma unroll
        for (int nt = 0; nt < 2; ++nt)
#pragma unroll
            for (int r = 0; r < 4; ++r) {
                const int et = mt * 16 + l4 * 4 + r;
                Hl[et * 34 + nt * 16 + l15] = fmaxf(acc1[mt][nt][r], 0.0f);
            }

    Frag A2[4];
#pragma unroll
    for (int mt = 0; mt < 4; ++mt) {
        const float* hb = &Hl[(mt * 16 + l15) * 34 + l4 * 8];
        const float2 g0 = *reinterpret_cast<const float2*>(hb + 0);
        const float2 g1 = *reinterpret_cast<const float2*>(hb + 2);
        const float2 g2 = *reinterpret_cast<const float2*>(hb + 4);
        const float2 g3 = *reinterpret_cast<const float2*>(hb + 6);
        A2[mt].u[0] = packrn(g0.x, g0.y);
        A2[mt].u[1] = packrn(g1.x, g1.y);
        A2[mt].u[2] = packrn(g2.x, g2.y);
        A2[mt].u[3] = packrn(g3.x, g3.y);
    }

    Frag B2f[4];
#pragma unroll
    for (int nt = 0; nt < 4; ++nt) {
        const uint4 q = *reinterpret_cast<const uint4*>(
            &PW2[(nt * 16 + l15) * 16 + l4 * 4]);
        B2f[nt].u[0] = q.x; B2f[nt].u[1] = q.y;
        B2f[nt].u[2] = q.z; B2f[nt].u[3] = q.w;
    }

#pragma unroll
    for (int nt = 0; nt < 4; ++nt) {
        const float b2v = b2[nt * 16 + l15];
        f32x4 a2c[4];
#pragma unroll
        for (int mt = 0; mt < 4; ++mt) {
            a2c[mt] = (f32x4){0.f, 0.f, 0.f, 0.f};
            a2c[mt] = __builtin_amdgcn_mfma_f32_16x16x32_bf16(
                A2[mt].v, B2f[nt].v, a2c[mt], 0, 0, 0);
        }
        const int j = nt * 16 + l15;
#pragma unroll
        for (int mt = 0; mt < 4; ++mt)
#pragma unroll
            for (int rp2 = 0; rp2 < 2; ++rp2) {
                const int q2 = mt * 8 + l4 * 2 + rp2;
                const float v0 = fmaxf(a2c[mt][rp2 * 2]     + b2v, 0.0f);
                const float v1 = fmaxf(a2c[mt][rp2 * 2 + 1] + b2v, 0.0f);
                smem[q2 * 64 + (j ^ (((q2 >> 1) & 1) << 4))] = packrn(v0, v1);
            }
    }

    const int n0 = nrange.x, n1 = nrange.y;
    for (int n = n0; n <= n1; ++n) {
        const int s0 = offs[n], t0 = offs[n + 1];
        const int sl = max(s0, e0) - e0, tl = min(t0, e1) - e0;
        float sum = 0.0f, mx = 0.0f;
        int q = sl;
        if (q < tl && (q & 1)) {
            const int q2 = q >> 1;
            const uint32_t wv = smem[q2 * 64 + (lane ^ (((q2 >> 1) & 1) << 4))];
            const float v = bf16_to_f(wv >> 16);
            sum += v; mx = fmaxf(mx, v); ++q;
        }
        for (; q + 1 < tl; q += 2) {
            const int q2 = q >> 1;
            const uint32_t wv = smem[q2 * 64 + (lane ^ (((q2 >> 1) & 1) << 4))];
            const float v0 = bf16_to_f(wv & 0xffffu), v1 = bf16_to_f(wv >> 16);
            sum += v0 + v1; mx = fmaxf(mx, fmaxf(v0, v1));
        }
        if (q < tl) {
            const int q2 = q >> 1;
            const uint32_t wv = smem[q2 * 64 + (lane ^ (((q2 >> 1) & 1) << 4))];
            const float v = bf16_to_f(wv & 0xffffu);
            sum += v; mx = fmaxf(mx, v);
        }
        float* sp = agg_sum  + (size_t)n * FMSG + lane;
        int*   mp = agg_maxb + (size_t)n * FMSG + lane;
        if (s0 >= e0 && t0 <= e1) {
            *sp = sum;
            *mp = __float_as_int(mx);
        } else {
            unsafeAtomicAdd(sp, sum);
            atomicMax(mp, __float_as_int(mx));
        }
    }
}

// ---------------------------------------------------------------------------
// node_mfma, identity-extended GEMM1 (K=192):
//   h = relu( [mean|max|Qc|Qu[batch]] @ [W3m; I; I] )
// ---------------------------------------------------------------------------
__global__ __launch_bounds__(256) void node_mfma(
    const float* __restrict__ Qc, const float* __restrict__ Qu,
    const int*   __restrict__ batch,
    const uint32_t* __restrict__ PW3, const uint32_t* __restrict__ PW4,
    const float* __restrict__ b4,
    const float* __restrict__ agg_sum, const int* __restrict__ agg_maxb,
    const int*   __restrict__ offs,
    float* __restrict__ out, int N)
{
    __shared__ float Hl_all[4 * 32 * 34];
    const int w    = threadIdx.x >> 6;
    float* Hl      = Hl_all + w * (32 * 34);
    const int lane = threadIdx.x & 63;
    const int l15  = lane & 15;
    const int l4   = lane >> 4;
    const int n0   = blockIdx.x * 128 + w * 32;
    if (n0 >= N) return;

    int   arn[2], gb[2];
    float ainv[2];
#pragma unroll
    for (int mt = 0; mt < 2; ++mt) {
        arn[mt] = min(n0 + mt * 16 + l15, N - 1);
        const int deg = offs[arn[mt] + 1] - offs[arn[mt]];
        ainv[mt] = (deg > 0) ? 1.0f / (float)deg : 0.0f;
        gb[mt]  = batch[arn[mt]];
    }

    f32x4 acc1[2][2];
#pragma unroll
    for (int mt = 0; mt < 2; ++mt)
#pragma unroll
        for (int nt = 0; nt < 2; ++nt)
            acc1[mt][nt] = (f32x4){0.f, 0.f, 0.f, 0.f};

#pragma unroll
    for (int ks = 0; ks < 6; ++ks) {
        Frag Bk[2];
#pragma unroll
        for (int nt = 0; nt < 2; ++nt) {
            const uint4 q = *reinterpret_cast<const uint4*>(
                &PW3[(nt * 16 + l15) * 96 + ks * 16 + l4 * 4]);
            Bk[nt].u[0] = q.x; Bk[nt].u[1] = q.y;
            Bk[nt].u[2] = q.z; Bk[nt].u[3] = q.w;
        }
        Frag A[2];
        if (ks < 2) {
#pragma unroll
            for (int mt = 0; mt < 2; ++mt) {
                const float4* gp = reinterpret_cast<const float4*>(
                    agg_sum + (size_t)arn[mt] * FMSG + ks * 32 + l4 * 8);
                const float4 f0 = gp[0], f1 = gp[1];
                const float s = ainv[mt];
                A[mt].u[0] = packrn(f0.x * s, f0.y * s);
                A[mt].u[1] = packrn(f0.z * s, f0.w * s);
                A[mt].u[2] = packrn(f1.x * s, f1.y * s);
                A[mt].u[3] = packrn(f1.z * s, f1.w * s);
            }
        } else if (ks < 4) {
#pragma unroll
            for (int mt = 0; mt < 2; ++mt) {
                const uint4* gp = reinterpret_cast<const uint4*>(
                    agg_maxb + (size_t)arn[mt] * FMSG + (ks - 2) * 32 + l4 * 8);
                const uint4 u0 = gp[0], u1 = gp[1];
                A[mt].u[0] = packrn(__uint_as_float(u0.x), __uint_as_float(u0.y));
                A[mt].u[1] = packrn(__uint_as_float(u0.z), __uint_as_float(u0.w));
                A[mt].u[2] = packrn(__uint_as_float(u1.x), __uint_as_float(u1.y));
                A[mt].u[3] = packrn(__uint_as_float(u1.z), __uint_as_float(u1.w));
            }
        } else {
#pragma unroll
            for (int mt = 0; mt < 2; ++mt) {
                const float* src = (ks == 4)
                    ? Qc + (size_t)arn[mt] * HIDN + l4 * 8
                    : Qu + (size_t)gb[mt]  * HIDN + l4 * 8;
                const float4 f0 = *reinterpret_cast<const float4*>(src);
                const float4 f1 = *reinterpret_cast<const float4*>(src + 4);
                A[mt].u[0] = packrn(f0.x, f0.y);
                A[mt].u[1] = packrn(f0.z, f0.w);
                A[mt].u[2] = packrn(f1.x, f1.y);
                A[mt].u[3] = packrn(f1.z, f1.w);
            }
        }
#pragma unroll
        for (int mt = 0; mt < 2; ++mt)
#pragma unroll
            for (int nt = 0; nt < 2; ++nt)
                acc1[mt][nt] = __builtin_amdgcn_mfma_f32_16x16x32_bf16(
                    A[mt].v, Bk[nt].v, acc1[mt][nt], 0, 0, 0);
    }

#pragma unroll
    for (int mt = 0; mt < 2; ++mt)
#pragma unroll
        for (int nt = 0; nt < 2; ++nt)
#pragma unroll
            for (int r = 0; r < 4; ++r) {
                const int rw = mt * 16 + l4 * 4 + r;
                Hl[rw * 34 + nt * 16 + l15] = fmaxf(acc1[mt][nt][r], 0.0f);
            }

    Frag A2[2];
#pragma unroll
    for (int mt = 0; mt < 2; ++mt) {
        const float* hb = &Hl[(mt * 16 + l15) * 34 + l4 * 8];
        const float2 g0 = *reinterpret_cast<const float2*>(hb + 0);
        const float2 g1 = *reinterpret_cast<const float2*>(hb + 2);
        const float2 g2 = *reinterpret_cast<const float2*>(hb + 4);
        const float2 g3 = *reinterpret_cast<const float2*>(hb + 6);
        A2[mt].u[0] = packrn(g0.x, g0.y);
        A2[mt].u[1] = packrn(g1.x, g1.y);
        A2[mt].u[2] = packrn(g2.x, g2.y);
        A2[mt].u[3] = packrn(g3.x, g3.y);
    }

#pragma unroll
    for (int nt = 0; nt < 8; ++nt) {
        Frag B4f;
        const uint4 q = *reinterpret_cast<const uint4*>(
            &PW4[(nt * 16 + l15) * 16 + l4 * 4]);
        B4f.u[0] = q.x; B4f.u[1] = q.y; B4f.u[2] = q.z; B4f.u[3] = q.w;
        const float b4v = b4[nt * 16 + l15];
        f32x4 tacc[2];
#pragma unroll
        for (int mt = 0; mt < 2; ++mt) {
            tacc[mt] = (f32x4){0.f, 0.f, 0.f, 0.f};
            tacc[mt] = __builtin_amdgcn_mfma_f32_16x16x32_bf16(
                A2[mt].v, B4f.v, tacc[mt], 0, 0, 0);
        }
#pragma unroll
        for (int mt = 0; mt < 2; ++mt)
#pragma unroll
            for (int r = 0; r < 4; ++r) {
                const int node = n0 + mt * 16 + l4 * 4 + r;
                if (node < N)
                    out[(size_t)node * FOUT + nt * 16 + l15] =
                        fmaxf(tacc[mt][r] + b4v, 0.0f);
            }
    }
}

// ===========================================================================
extern "C" void kernel_launch(void* const* d_in, const int* in_sizes, int n_in,
                              void* d_out, int out_size, void* d_ws, size_t ws_size,
                              hipStream_t stream)
{
    const float* x     = (const float*)d_in[0];
    const int*   ei    = (const int*)  d_in[1];
    const float* ea    = (const float*)d_in[2];
    const float* u     = (const float*)d_in[3];
    const int*   batch = (const int*)  d_in[4];
    const float* W1    = (const float*)d_in[5];
    const float* b1    = (const float*)d_in[6];
    const float* W2    = (const float*)d_in[7];
    const float* b2    = (const float*)d_in[8];
    const float* W3    = (const float*)d_in[9];
    const float* b3    = (const float*)d_in[10];
    const float* W4    = (const float*)d_in[11];
    const float* b4    = (const float*)d_in[12];
    float* out = (float*)d_out;

    const int N = in_sizes[0] / FN;   // 50000
    const int E = in_sizes[1] / 2;    // 800000
    const int G = in_sizes[3] / FN;   // 64
    const int NT = (E + 63) / 64;     // 64-edge tiles

    char* wp = (char*)d_ws;
    auto take = [&](size_t bytes) -> void* {
        void* r = (void*)wp;
        wp += (bytes + 255) & ~(size_t)255;
        return r;
    };
    float*    agg_sum  = (float*)   take((size_t)N * FMSG * 4);
    int*      agg_maxb = (int*)     take((size_t)N * FMSG * 4);
    char*     zero_end = wp;                       // agg zero span (in mega_prep)
    int*      cnt      = (int*)     take((size_t)N * 4);
    int*      offs     = (int*)     take(((size_t)N + 1) * 4);
    int*      rank     = (int*)     take((size_t)E * 4);
    int4*     re4      = (int4*)    take((size_t)E * 16);
    int2*     ntile    = (int2*)    take((size_t)NT * 8);
    float*    Pa       = (float*)   take((size_t)N * HIDN * 4);
    float*    Pb       = (float*)   take((size_t)N * HIDN * 4);
    float*    Qc       = (float*)   take((size_t)N * HIDN * 4);
    float*    Qu       = (float*)   take((size_t)G * HIDN * 4);
    uint32_t* PW1      = (uint32_t*)take(2048 * 4);
    uint32_t* PW2      = (uint32_t*)take(1024 * 4);
    uint32_t* PW3      = (uint32_t*)take(3072 * 4);
    uint32_t* PW4      = (uint32_t*)take(2048 * 4);
    int*      part     = (int*)     take(64 * 4);

    const int BH  = (E + 2047) / 2048;             // hist blocks (8 edges/thread)
    const int BPN = (N + 255) / 256;               // node_pre blocks
    const int BZ  = 256;                           // agg-zero blocks
    const int NB  = (N + 2047) / 2048;             // scan blocks
    const int SB  = (E + 255) / 256;               // scatter blocks
    const int TB  = (NT + 255) / 256;              // ntile blocks
    const size_t zquads = (size_t)(zero_end - (char*)agg_sum) / 16;

    zero_cnt_kernel<<<(N + 255) / 256, 256, 0, stream>>>(cnt, N);
    mega_prep_kernel<<<BH + BPN + 1 + BZ, 256, 0, stream>>>(
        ei, cnt, rank, x, u, W1, b1, W2, W3, b3, W4,
        Pa, Pb, Qc, Qu, PW1, PW2, PW3, PW4,
        (uint4*)agg_sum, zquads, E, N, G, BH, BPN, BZ);
    scanA_kernel   <<<NB, 256, 0, stream>>>(cnt, part, N);
    scanC_kernel   <<<NB, 256, 0, stream>>>(cnt, part, offs, NB, N, E);
    scatter_ntile_kernel<<<SB + TB, 256, 0, stream>>>(
        ei, offs, rank, re4, ntile, E, N, NT, SB);
    fused_edge_mfma<<<(NT + 1) / 2, 128, 0, stream>>>(
        ea, PW1, PW2, b2, Pa, Pb, re4, offs, ntile, agg_sum, agg_maxb, N, E, NT);
    node_mfma      <<<(N + 127) / 128, 256, 0, stream>>>(
        Qc, Qu, batch, PW3, PW4, b4, agg_sum, agg_maxb, offs, out, N);
}

// Round 14
// 197.033 us; speedup vs baseline: 1.2490x; 1.0029x over previous
//
#include <hip/hip_runtime.h>
#include <hip/hip_bf16.h>
#include <stdint.h>

constexpr int FN   = 64;
constexpr int HIDN = 32;
constexpr int FMSG = 64;
constexpr int FOUT = 128;

using short8 = __attribute__((ext_vector_type(8))) short;
using f32x4  = __attribute__((ext_vector_type(4))) float;

union Frag { short8 v; uint32_t u[4]; };

__device__ __forceinline__ uint32_t packrn(float a, float b) {
    union { __hip_bfloat162 h; uint32_t u; } cv;
    cv.h = __float22bfloat162_rn(make_float2(a, b));   // v_cvt_pk_bf16_f32
    return cv.u;
}
__device__ __forceinline__ float bf16_to_f(uint32_t h16) {
    return __uint_as_float(h16 << 16);
}

__device__ __forceinline__ int node_of(const int* __restrict__ offs, int N, int target) {
    int l = 0, r = N + 1;
    while (l + 1 < r) {
        const int m = (l + r) >> 1;
        if (offs[m] <= target) l = m; else r = m;
    }
    return l;
}

// ---------------------------------------------------------------------------
__global__ __launch_bounds__(256) void zero_cnt_kernel(int* __restrict__ cnt, int N)
{
    const int i = blockIdx.x * 256 + threadIdx.x;
    if (i < N) cnt[i] = 0;
}

// ---------------------------------------------------------------------------
// mega_prep: [0,BH) hist (8 atomics/thread) | [BH,BH+BPN) node_pre
//          | [BH+BPN] pack (identity-extended) + Qu | [+1, +BZ) agg zero
// ---------------------------------------------------------------------------
__global__ __launch_bounds__(256) void mega_prep_kernel(
    const int* __restrict__ ei, int* __restrict__ cnt, int* __restrict__ rank,
    const float* __restrict__ x, const float* __restrict__ u,
    const float* __restrict__ W1, const float* __restrict__ b1,
    const float* __restrict__ W2,
    const float* __restrict__ W3, const float* __restrict__ b3,
    const float* __restrict__ W4,
    float* __restrict__ Pa, float* __restrict__ Pb, float* __restrict__ Qc,
    float* __restrict__ Qu,
    uint32_t* __restrict__ PW1, uint32_t* __restrict__ PW2,
    uint32_t* __restrict__ PW3, uint32_t* __restrict__ PW4,
    uint4* __restrict__ zbase, size_t zquads,
    int E, int N, int G, int BH, int BPN, int BZ)
{
    __shared__ float xs_all[4 * 64 * 33];
    const int b   = blockIdx.x;
    const int tid = threadIdx.x;

    if (b < BH) {
        const int base = (b * 256 + tid) * 8;
        if (base + 8 <= E) {
            const int4 c0 = *reinterpret_cast<const int4*>(ei + E + base);
            const int4 c1 = *reinterpret_cast<const int4*>(ei + E + base + 4);
            int4 r0, r1;
            r0.x = atomicAdd(cnt + c0.x, 1);
            r0.y = atomicAdd(cnt + c0.y, 1);
            r0.z = atomicAdd(cnt + c0.z, 1);
            r0.w = atomicAdd(cnt + c0.w, 1);
            r1.x = atomicAdd(cnt + c1.x, 1);
            r1.y = atomicAdd(cnt + c1.y, 1);
            r1.z = atomicAdd(cnt + c1.z, 1);
            r1.w = atomicAdd(cnt + c1.w, 1);
            *reinterpret_cast<int4*>(rank + base)     = r0;
            *reinterpret_cast<int4*>(rank + base + 4) = r1;
        } else {
            for (int e = base; e < E; ++e) rank[e] = atomicAdd(cnt + ei[E + e], 1);
        }
        return;
    }
    if (b < BH + BPN) {
        const int w    = tid >> 6;
        const int lane = tid & 63;
        float* xs = xs_all + w * (64 * 33);
        const int nbase = (b - BH) * 256 + w * 64;
        if (nbase >= N) return;

        float a[HIDN], bq[HIDN], cc[HIDN];
#pragma unroll
        for (int j = 0; j < HIDN; ++j) { a[j] = b1[j]; bq[j] = 0.0f; cc[j] = b3[j]; }

#pragma unroll
        for (int c = 0; c < 2; ++c) {
#pragma unroll
            for (int i = 0; i < 8; ++i) {
                const int idx = i * 64 + lane;
                const int row = idx >> 3, cq = idx & 7;
                const int nr  = min(nbase + row, N - 1);
                const float4 v = *reinterpret_cast<const float4*>(
                    x + (size_t)nr * FN + c * 32 + cq * 4);
                float* d = xs + row * 33 + cq * 4;
                d[0] = v.x; d[1] = v.y; d[2] = v.z; d[3] = v.w;
            }
            const float* xr = xs + lane * 33;
#pragma unroll 2
            for (int k = 0; k < 32; k += 4) {
                const float v0 = xr[k], v1 = xr[k + 1], v2 = xr[k + 2], v3 = xr[k + 3];
                const int kg = c * 32 + k;
                const float* wa = W1 + kg * HIDN;
                const float* wb = W1 + FN * HIDN + kg * HIDN;
                const float* wc = W3 + kg * HIDN;
#pragma unroll
                for (int j = 0; j < HIDN; ++j) {
                    float aj = a[j], bj = bq[j], cj = cc[j];
                    aj = fmaf(v0, wa[j], aj);            bj = fmaf(v0, wb[j], bj);            cj = fmaf(v0, wc[j], cj);
                    aj = fmaf(v1, wa[HIDN + j], aj);     bj = fmaf(v1, wb[HIDN + j], bj);     cj = fmaf(v1, wc[HIDN + j], cj);
                    aj = fmaf(v2, wa[2 * HIDN + j], aj); bj = fmaf(v2, wb[2 * HIDN + j], bj); cj = fmaf(v2, wc[2 * HIDN + j], cj);
                    aj = fmaf(v3, wa[3 * HIDN + j], aj); bj = fmaf(v3, wb[3 * HIDN + j], bj); cj = fmaf(v3, wc[3 * HIDN + j], cj);
                    a[j] = aj; bq[j] = bj; cc[j] = cj;
                }
            }
        }
        const int n = nbase + lane;
        if (n >= N) return;
        float4* pa = reinterpret_cast<float4*>(Pa + (size_t)n * HIDN);
        float4* pb = reinterpret_cast<float4*>(Pb + (size_t)n * HIDN);
        float4* qc = reinterpret_cast<float4*>(Qc + (size_t)n * HIDN);
#pragma unroll
        for (int q = 0; q < HIDN / 4; ++q) {
            pa[q] = make_float4(a[4*q], a[4*q+1], a[4*q+2], a[4*q+3]);
            pb[q] = make_float4(bq[4*q], bq[4*q+1], bq[4*q+2], bq[4*q+3]);
            qc[q] = make_float4(cc[4*q], cc[4*q+1], cc[4*q+2], cc[4*q+3]);
        }
        return;
    }
    if (b == BH + BPN) {
        // ---- pack weights (identity-extended) + Qu ----
        const float* WC = W1 + 2 * FN * HIDN;
        for (int i = tid; i < 2048; i += 256) {          // PW1X[j<32][k2<64]
            const int j = i >> 6, k2 = i & 63;
            uint32_t v;
            if (k2 < 32) {
                v = packrn(WC[(2 * k2) * HIDN + j], WC[(2 * k2 + 1) * HIDN + j]);
            } else if (k2 < 48) {
                const int r0 = 2 * (k2 - 32);
                v = packrn(r0 == j ? 1.0f : 0.0f, r0 + 1 == j ? 1.0f : 0.0f);
            } else {
                const int r0 = 2 * (k2 - 48);
                v = packrn(r0 == j ? 1.0f : 0.0f, r0 + 1 == j ? 1.0f : 0.0f);
            }
            PW1[i] = v;
        }
        for (int i = tid; i < 1024; i += 256) {          // PW2[j<64][k2<16]
            const int j = i >> 4, k2 = i & 15;
            PW2[i] = packrn(W2[(2 * k2) * FMSG + j], W2[(2 * k2 + 1) * FMSG + j]);
        }
        const float* W3m = W3 + 64 * HIDN;               // rows 64..191 (mean|max)
        for (int i = tid; i < 3072; i += 256) {          // PW3X[j<32][k2<96]
            const int j = i / 96, k2 = i - j * 96;
            uint32_t v;
            if (k2 < 64) {
                v = packrn(W3m[(2 * k2) * HIDN + j], W3m[(2 * k2 + 1) * HIDN + j]);
            } else if (k2 < 80) {
                const int r0 = 2 * (k2 - 64);
                v = packrn(r0 == j ? 1.0f : 0.0f, r0 + 1 == j ? 1.0f : 0.0f);
            } else {
                const int r0 = 2 * (k2 - 80);
                v = packrn(r0 == j ? 1.0f : 0.0f, r0 + 1 == j ? 1.0f : 0.0f);
            }
            PW3[i] = v;
        }
        for (int i = tid; i < 2048; i += 256) {          // PW4[j<128][k2<16]
            const int j = i >> 4, k2 = i & 15;
            PW4[i] = packrn(W4[(2 * k2) * FOUT + j], W4[(2 * k2 + 1) * FOUT + j]);
        }
        const float* W3u = W3 + 192 * HIDN;
        for (int i = tid; i < G * HIDN; i += 256) {
            const int g = i >> 5, j = i & 31;
            const float* ur = u + (size_t)g * FN;
            float acc = 0.0f;
#pragma unroll 8
            for (int k = 0; k < FN; ++k) acc = fmaf(ur[k], W3u[k * HIDN + j], acc);
            Qu[i] = acc;
        }
        return;
    }
    const size_t stride = (size_t)BZ * 256;
    const uint4 z = make_uint4(0u, 0u, 0u, 0u);
    for (size_t i = (size_t)(b - BH - BPN - 1) * 256 + tid; i < zquads; i += stride)
        zbase[i] = z;
}

// ---------------------------------------------------------------------------
__global__ __launch_bounds__(256) void scanA_kernel(
    const int* __restrict__ cnt, int* __restrict__ part, int N)
{
    __shared__ int red[256];
    const int tid  = threadIdx.x;
    const int base = blockIdx.x * 2048 + tid * 8;
    int s = 0;
    if (base + 8 <= N) {
        const int4 a = *reinterpret_cast<const int4*>(cnt + base);
        const int4 b = *reinterpret_cast<const int4*>(cnt + base + 4);
        s = a.x + a.y + a.z + a.w + b.x + b.y + b.z + b.w;
    } else {
        for (int i = base; i < min(base + 8, N); ++i) s += cnt[i];
    }
    red[tid] = s;
    __syncthreads();
    for (int d = 128; d > 0; d >>= 1) {
        if (tid < d) red[tid] += red[tid + d];
        __syncthreads();
    }
    if (tid == 0) part[blockIdx.x] = red[0];
}

__global__ __launch_bounds__(256) void scanC_kernel(
    const int* __restrict__ cnt, const int* __restrict__ part,
    int* __restrict__ offs, int NB, int N, int E)
{
    __shared__ int sb[256];
    const int tid  = threadIdx.x;
    int px = 0;
    for (int i = 0; i < (int)blockIdx.x; ++i) px += part[i];

    const int base = blockIdx.x * 2048 + tid * 8;
    int v[8];
    int tsum = 0;
#pragma unroll
    for (int q = 0; q < 8; ++q) {
        const int i = base + q;
        v[q] = (i < N) ? cnt[i] : 0;
        tsum += v[q];
    }
    sb[tid] = tsum;
    __syncthreads();
    for (int d = 1; d < 256; d <<= 1) {
        const int t = (tid >= d) ? sb[tid - d] : 0;
        __syncthreads();
        sb[tid] += t;
        __syncthreads();
    }
    int run = px + sb[tid] - tsum;
#pragma unroll
    for (int q = 0; q < 8; ++q) {
        const int i = base + q;
        if (i < N) offs[i] = run;
        run += v[q];
    }
    if (blockIdx.x == 0 && tid == 0) offs[N] = E;
}

// ---------------------------------------------------------------------------
__global__ __launch_bounds__(256) void scatter_ntile_kernel(
    const int* __restrict__ ei, const int* __restrict__ offs,
    const int* __restrict__ rank, int4* __restrict__ re4,
    int2* __restrict__ ntile, int E, int N, int NT, int SB)
{
    const int tid = threadIdx.x;
    if ((int)blockIdx.x < SB) {
        const int e = blockIdx.x * 256 + tid;
        if (e >= E) return;
        const int row = ei[e];
        const int col = ei[E + e];
        const int pos = offs[col] + rank[e];
        re4[pos] = make_int4(row, col, e, 0);
    } else {
        const int t = ((int)blockIdx.x - SB) * 256 + tid;
        if (t >= NT) return;
        const int a = node_of(offs, N, t * 64);
        const int b = node_of(offs, N, min(t * 64 + 63, E - 1));
        ntile[t] = make_int2(a, b);
    }
}

// ---------------------------------------------------------------------------
// Barrier-free MFMA fused edge kernel. GEMM1 restructured into two explicit
// load-stages (all ea loads in flight -> one wait; then all Pa/Pb loads).
// ---------------------------------------------------------------------------
__global__ __launch_bounds__(128) void fused_edge_mfma(
    const float* __restrict__ ea,
    const uint32_t* __restrict__ PW1, const uint32_t* __restrict__ PW2,
    const float* __restrict__ b2,
    const float* __restrict__ Pa, const float* __restrict__ Pb,
    const int4* __restrict__ re4, const int* __restrict__ offs,
    const int2* __restrict__ ntile,
    float* __restrict__ agg_sum, int* __restrict__ agg_maxb,
    int N, int E, int NT)
{
    __shared__ uint32_t smem_all[2 * 64 * 34];
    const int w    = threadIdx.x >> 6;
    const int t    = blockIdx.x * 2 + w;
    if (t >= NT) return;
    uint32_t* smem = smem_all + w * (64 * 34);
    const int lane = threadIdx.x & 63;
    const int l15  = lane & 15;
    const int l4   = lane >> 4;
    const int e0   = t * 64;
    const int e1   = min(e0 + 64, E);
    const int2 nrange = ntile[t];

    const int p = e0 + lane;
    const int4 rce = re4[min(p, E - 1)];

    int er[4], rr[4], cr[4];
#pragma unroll
    for (int mt = 0; mt < 4; ++mt) {
        er[mt] = __shfl(rce.z, mt * 16 + l15, 64);
        rr[mt] = __shfl(rce.x, mt * 16 + l15, 64);
        cr[mt] = __shfl(rce.y, mt * 16 + l15, 64);
    }

    f32x4 acc1[4][2];
#pragma unroll
    for (int mt = 0; mt < 4; ++mt)
#pragma unroll
        for (int nt = 0; nt < 2; ++nt)
            acc1[mt][nt] = (f32x4){0.f, 0.f, 0.f, 0.f};

    // ---- stage 1: ALL 16 ea raw loads issued back-to-back ----
    float4 raw[4][2][2];   // [mt][slot][half]
#pragma unroll
    for (int mt = 0; mt < 4; ++mt)
#pragma unroll
        for (int ks = 0; ks < 2; ++ks) {
            const float* src = ea + (size_t)er[mt] * FN + ks * 32 + l4 * 8;
            raw[mt][ks][0] = *reinterpret_cast<const float4*>(src);
            raw[mt][ks][1] = *reinterpret_cast<const float4*>(src + 4);
        }
    // compute ks = 0,1 (ea)
#pragma unroll
    for (int ks = 0; ks < 2; ++ks) {
        Frag Bk[2];
#pragma unroll
        for (int nt = 0; nt < 2; ++nt) {
            const uint4 q = *reinterpret_cast<const uint4*>(
                &PW1[(nt * 16 + l15) * 64 + ks * 16 + l4 * 4]);
            Bk[nt].u[0] = q.x; Bk[nt].u[1] = q.y;
            Bk[nt].u[2] = q.z; Bk[nt].u[3] = q.w;
        }
        Frag A[4];
#pragma unroll
        for (int mt = 0; mt < 4; ++mt) {
            const float4 f0 = raw[mt][ks][0], f1 = raw[mt][ks][1];
            A[mt].u[0] = packrn(f0.x, f0.y);
            A[mt].u[1] = packrn(f0.z, f0.w);
            A[mt].u[2] = packrn(f1.x, f1.y);
            A[mt].u[3] = packrn(f1.z, f1.w);
        }
#pragma unroll
        for (int mt = 0; mt < 4; ++mt)
#pragma unroll
            for (int nt = 0; nt < 2; ++nt)
                acc1[mt][nt] = __builtin_amdgcn_mfma_f32_16x16x32_bf16(
                    A[mt].v, Bk[nt].v, acc1[mt][nt], 0, 0, 0);
    }
    // ---- stage 2: ALL 16 Pa/Pb raw loads (reuse raw regs) ----
#pragma unroll
    for (int mt = 0; mt < 4; ++mt) {
        const float* sa = Pa + (size_t)rr[mt] * HIDN + l4 * 8;
        const float* sb = Pb + (size_t)cr[mt] * HIDN + l4 * 8;
        raw[mt][0][0] = *reinterpret_cast<const float4*>(sa);
        raw[mt][0][1] = *reinterpret_cast<const float4*>(sa + 4);
        raw[mt][1][0] = *reinterpret_cast<const float4*>(sb);
        raw[mt][1][1] = *reinterpret_cast<const float4*>(sb + 4);
    }
    // compute ks = 2 (Pa, slot 0), ks = 3 (Pb, slot 1)
#pragma unroll
    for (int ks = 2; ks < 4; ++ks) {
        Frag Bk[2];
#pragma unroll
        for (int nt = 0; nt < 2; ++nt) {
            const uint4 q = *reinterpret_cast<const uint4*>(
                &PW1[(nt * 16 + l15) * 64 + ks * 16 + l4 * 4]);
            Bk[nt].u[0] = q.x; Bk[nt].u[1] = q.y;
            Bk[nt].u[2] = q.z; Bk[nt].u[3] = q.w;
        }
        Frag A[4];
#pragma unroll
        for (int mt = 0; mt < 4; ++mt) {
            const float4 f0 = raw[mt][ks - 2][0], f1 = raw[mt][ks - 2][1];
            A[mt].u[0] = packrn(f0.x, f0.y);
            A[mt].u[1] = packrn(f0.z, f0.w);
            A[mt].u[2] = packrn(f1.x, f1.y);
            A[mt].u[3] = packrn(f1.z, f1.w);
        }
#pragma unroll
        for (int mt = 0; mt < 4; ++mt)
#pragma unroll
            for (int nt = 0; nt < 2; ++nt)
                acc1[mt][nt] = __builtin_amdgcn_mfma_f32_16x16x32_bf16(
                    A[mt].v, Bk[nt].v, acc1[mt][nt], 0, 0, 0);
    }

    // ---- h -> LDS (wave-local transpose), relu ----
    float* Hl = reinterpret_cast<float*>(smem);
#pragma unroll
    for (int mt = 0; mt < 4; ++mt)
#pragma unroll
        for (int nt = 0; nt < 2; ++nt)
#pragma unroll
            for (int r = 0; r < 4; ++r) {
                const int et = mt * 16 + l4 * 4 + r;
                Hl[et * 34 + nt * 16 + l15] = fmaxf(acc1[mt][nt][r], 0.0f);
            }

    Frag A2[4];
#pragma unroll
    for (int mt = 0; mt < 4; ++mt) {
        const float* hb = &Hl[(mt * 16 + l15) * 34 + l4 * 8];
        const float2 g0 = *reinterpret_cast<const float2*>(hb + 0);
        const float2 g1 = *reinterpret_cast<const float2*>(hb + 2);
        const float2 g2 = *reinterpret_cast<const float2*>(hb + 4);
        const float2 g3 = *reinterpret_cast<const float2*>(hb + 6);
        A2[mt].u[0] = packrn(g0.x, g0.y);
        A2[mt].u[1] = packrn(g1.x, g1.y);
        A2[mt].u[2] = packrn(g2.x, g2.y);
        A2[mt].u[3] = packrn(g3.x, g3.y);
    }

    Frag B2f[4];
#pragma unroll
    for (int nt = 0; nt < 4; ++nt) {
        const uint4 q = *reinterpret_cast<const uint4*>(
            &PW2[(nt * 16 + l15) * 16 + l4 * 4]);
        B2f[nt].u[0] = q.x; B2f[nt].u[1] = q.y;
        B2f[nt].u[2] = q.z; B2f[nt].u[3] = q.w;
    }

#pragma unroll
    for (int nt = 0; nt < 4; ++nt) {
        const float b2v = b2[nt * 16 + l15];
        f32x4 a2c[4];
#pragma unroll
        for (int mt = 0; mt < 4; ++mt) {
            a2c[mt] = (f32x4){0.f, 0.f, 0.f, 0.f};
            a2c[mt] = __builtin_amdgcn_mfma_f32_16x16x32_bf16(
                A2[mt].v, B2f[nt].v, a2c[mt], 0, 0, 0);
        }
        const int j = nt * 16 + l15;
#pragma unroll
        for (int mt = 0; mt < 4; ++mt)
#pragma unroll
            for (int rp2 = 0; rp2 < 2; ++rp2) {
                const int q2 = mt * 8 + l4 * 2 + rp2;
                const float v0 = fmaxf(a2c[mt][rp2 * 2]     + b2v, 0.0f);
                const float v1 = fmaxf(a2c[mt][rp2 * 2 + 1] + b2v, 0.0f);
                smem[q2 * 64 + (j ^ (((q2 >> 1) & 1) << 4))] = packrn(v0, v1);
            }
    }

    const int n0 = nrange.x, n1 = nrange.y;
    for (int n = n0; n <= n1; ++n) {
        const int s0 = offs[n], t0 = offs[n + 1];
        const int sl = max(s0, e0) - e0, tl = min(t0, e1) - e0;
        float sum = 0.0f, mx = 0.0f;
        int q = sl;
        if (q < tl && (q & 1)) {
            const int q2 = q >> 1;
            const uint32_t wv = smem[q2 * 64 + (lane ^ (((q2 >> 1) & 1) << 4))];
            const float v = bf16_to_f(wv >> 16);
            sum += v; mx = fmaxf(mx, v); ++q;
        }
        for (; q + 1 < tl; q += 2) {
            const int q2 = q >> 1;
            const uint32_t wv = smem[q2 * 64 + (lane ^ (((q2 >> 1) & 1) << 4))];
            const float v0 = bf16_to_f(wv & 0xffffu), v1 = bf16_to_f(wv >> 16);
            sum += v0 + v1; mx = fmaxf(mx, fmaxf(v0, v1));
        }
        if (q < tl) {
            const int q2 = q >> 1;
            const uint32_t wv = smem[q2 * 64 + (lane ^ (((q2 >> 1) & 1) << 4))];
            const float v = bf16_to_f(wv & 0xffffu);
            sum += v; mx = fmaxf(mx, v);
        }
        float* sp = agg_sum  + (size_t)n * FMSG + lane;
        int*   mp = agg_maxb + (size_t)n * FMSG + lane;
        if (s0 >= e0 && t0 <= e1) {
            *sp = sum;
            *mp = __float_as_int(mx);
        } else {
            unsafeAtomicAdd(sp, sum);
            atomicMax(mp, __float_as_int(mx));
        }
    }
}

// ---------------------------------------------------------------------------
// node_mfma, identity-extended GEMM1 (K=192) — unchanged from R13.
// ---------------------------------------------------------------------------
__global__ __launch_bounds__(256) void node_mfma(
    const float* __restrict__ Qc, const float* __restrict__ Qu,
    const int*   __restrict__ batch,
    const uint32_t* __restrict__ PW3, const uint32_t* __restrict__ PW4,
    const float* __restrict__ b4,
    const float* __restrict__ agg_sum, const int* __restrict__ agg_maxb,
    const int*   __restrict__ offs,
    float* __restrict__ out, int N)
{
    __shared__ float Hl_all[4 * 32 * 34];
    const int w    = threadIdx.x >> 6;
    float* Hl      = Hl_all + w * (32 * 34);
    const int lane = threadIdx.x & 63;
    const int l15  = lane & 15;
    const int l4   = lane >> 4;
    const int n0   = blockIdx.x * 128 + w * 32;
    if (n0 >= N) return;

    int   arn[2], gb[2];
    float ainv[2];
#pragma unroll
    for (int mt = 0; mt < 2; ++mt) {
        arn[mt] = min(n0 + mt * 16 + l15, N - 1);
        const int deg = offs[arn[mt] + 1] - offs[arn[mt]];
        ainv[mt] = (deg > 0) ? 1.0f / (float)deg : 0.0f;
        gb[mt]  = batch[arn[mt]];
    }

    f32x4 acc1[2][2];
#pragma unroll
    for (int mt = 0; mt < 2; ++mt)
#pragma unroll
        for (int nt = 0; nt < 2; ++nt)
            acc1[mt][nt] = (f32x4){0.f, 0.f, 0.f, 0.f};

#pragma unroll
    for (int ks = 0; ks < 6; ++ks) {
        Frag Bk[2];
#pragma unroll
        for (int nt = 0; nt < 2; ++nt) {
            const uint4 q = *reinterpret_cast<const uint4*>(
                &PW3[(nt * 16 + l15) * 96 + ks * 16 + l4 * 4]);
            Bk[nt].u[0] = q.x; Bk[nt].u[1] = q.y;
            Bk[nt].u[2] = q.z; Bk[nt].u[3] = q.w;
        }
        Frag A[2];
        if (ks < 2) {
#pragma unroll
            for (int mt = 0; mt < 2; ++mt) {
                const float4* gp = reinterpret_cast<const float4*>(
                    agg_sum + (size_t)arn[mt] * FMSG + ks * 32 + l4 * 8);
                const float4 f0 = gp[0], f1 = gp[1];
                const float s = ainv[mt];
                A[mt].u[0] = packrn(f0.x * s, f0.y * s);
                A[mt].u[1] = packrn(f0.z * s, f0.w * s);
                A[mt].u[2] = packrn(f1.x * s, f1.y * s);
                A[mt].u[3] = packrn(f1.z * s, f1.w * s);
            }
        } else if (ks < 4) {
#pragma unroll
            for (int mt = 0; mt < 2; ++mt) {
                const uint4* gp = reinterpret_cast<const uint4*>(
                    agg_maxb + (size_t)arn[mt] * FMSG + (ks - 2) * 32 + l4 * 8);
                const uint4 u0 = gp[0], u1 = gp[1];
                A[mt].u[0] = packrn(__uint_as_float(u0.x), __uint_as_float(u0.y));
                A[mt].u[1] = packrn(__uint_as_float(u0.z), __uint_as_float(u0.w));
                A[mt].u[2] = packrn(__uint_as_float(u1.x), __uint_as_float(u1.y));
                A[mt].u[3] = packrn(__uint_as_float(u1.z), __uint_as_float(u1.w));
            }
        } else {
#pragma unroll
            for (int mt = 0; mt < 2; ++mt) {
                const float* src = (ks == 4)
                    ? Qc + (size_t)arn[mt] * HIDN + l4 * 8
                    : Qu + (size_t)gb[mt]  * HIDN + l4 * 8;
                const float4 f0 = *reinterpret_cast<const float4*>(src);
                const float4 f1 = *reinterpret_cast<const float4*>(src + 4);
                A[mt].u[0] = packrn(f0.x, f0.y);
                A[mt].u[1] = packrn(f0.z, f0.w);
                A[mt].u[2] = packrn(f1.x, f1.y);
                A[mt].u[3] = packrn(f1.z, f1.w);
            }
        }
#pragma unroll
        for (int mt = 0; mt < 2; ++mt)
#pragma unroll
            for (int nt = 0; nt < 2; ++nt)
                acc1[mt][nt] = __builtin_amdgcn_mfma_f32_16x16x32_bf16(
                    A[mt].v, Bk[nt].v, acc1[mt][nt], 0, 0, 0);
    }

#pragma unroll
    for (int mt = 0; mt < 2; ++mt)
#pragma unroll
        for (int nt = 0; nt < 2; ++nt)
#pragma unroll
            for (int r = 0; r < 4; ++r) {
                const int rw = mt * 16 + l4 * 4 + r;
                Hl[rw * 34 + nt * 16 + l15] = fmaxf(acc1[mt][nt][r], 0.0f);
            }

    Frag A2[2];
#pragma unroll
    for (int mt = 0; mt < 2; ++mt) {
        const float* hb = &Hl[(mt * 16 + l15) * 34 + l4 * 8];
        const float2 g0 = *reinterpret_cast<const float2*>(hb + 0);
        const float2 g1 = *reinterpret_cast<const float2*>(hb + 2);
        const float2 g2 = *reinterpret_cast<const float2*>(hb + 4);
        const float2 g3 = *reinterpret_cast<const float2*>(hb + 6);
        A2[mt].u[0] = packrn(g0.x, g0.y);
        A2[mt].u[1] = packrn(g1.x, g1.y);
        A2[mt].u[2] = packrn(g2.x, g2.y);
        A2[mt].u[3] = packrn(g3.x, g3.y);
    }

#pragma unroll
    for (int nt = 0; nt < 8; ++nt) {
        Frag B4f;
        const uint4 q = *reinterpret_cast<const uint4*>(
            &PW4[(nt * 16 + l15) * 16 + l4 * 4]);
        B4f.u[0] = q.x; B4f.u[1] = q.y; B4f.u[2] = q.z; B4f.u[3] = q.w;
        const float b4v = b4[nt * 16 + l15];
        f32x4 tacc[2];
#pragma unroll
        for (int mt = 0; mt < 2; ++mt) {
            tacc[mt] = (f32x4){0.f, 0.f, 0.f, 0.f};
            tacc[mt] = __builtin_amdgcn_mfma_f32_16x16x32_bf16(
                A2[mt].v, B4f.v, tacc[mt], 0, 0, 0);
        }
#pragma unroll
        for (int mt = 0; mt < 2; ++mt)
#pragma unroll
            for (int r = 0; r < 4; ++r) {
                const int node = n0 + mt * 16 + l4 * 4 + r;
                if (node < N)
                    out[(size_t)node * FOUT + nt * 16 + l15] =
                        fmaxf(tacc[mt][r] + b4v, 0.0f);
            }
    }
}

// ===========================================================================
extern "C" void kernel_launch(void* const* d_in, const int* in_sizes, int n_in,
                              void* d_out, int out_size, void* d_ws, size_t ws_size,
                              hipStream_t stream)
{
    const float* x     = (const float*)d_in[0];
    const int*   ei    = (const int*)  d_in[1];
    const float* ea    = (const float*)d_in[2];
    const float* u     = (const float*)d_in[3];
    const int*   batch = (const int*)  d_in[4];
    const float* W1    = (const float*)d_in[5];
    const float* b1    = (const float*)d_in[6];
    const float* W2    = (const float*)d_in[7];
    const float* b2    = (const float*)d_in[8];
    const float* W3    = (const float*)d_in[9];
    const float* b3    = (const float*)d_in[10];
    const float* W4    = (const float*)d_in[11];
    const float* b4    = (const float*)d_in[12];
    float* out = (float*)d_out;

    const int N = in_sizes[0] / FN;   // 50000
    const int E = in_sizes[1] / 2;    // 800000
    const int G = in_sizes[3] / FN;   // 64
    const int NT = (E + 63) / 64;     // 64-edge tiles

    char* wp = (char*)d_ws;
    auto take = [&](size_t bytes) -> void* {
        void* r = (void*)wp;
        wp += (bytes + 255) & ~(size_t)255;
        return r;
    };
    float*    agg_sum  = (float*)   take((size_t)N * FMSG * 4);
    int*      agg_maxb = (int*)     take((size_t)N * FMSG * 4);
    char*     zero_end = wp;                       // agg zero span (in mega_prep)
    int*      cnt      = (int*)     take((size_t)N * 4);
    int*      offs     = (int*)     take(((size_t)N + 1) * 4);
    int*      rank     = (int*)     take((size_t)E * 4);
    int4*     re4      = (int4*)    take((size_t)E * 16);
    int2*     ntile    = (int2*)    take((size_t)NT * 8);
    float*    Pa       = (float*)   take((size_t)N * HIDN * 4);
    float*    Pb       = (float*)   take((size_t)N * HIDN * 4);
    float*    Qc       = (float*)   take((size_t)N * HIDN * 4);
    float*    Qu       = (float*)   take((size_t)G * HIDN * 4);
    uint32_t* PW1      = (uint32_t*)take(2048 * 4);
    uint32_t* PW2      = (uint32_t*)take(1024 * 4);
    uint32_t* PW3      = (uint32_t*)take(3072 * 4);
    uint32_t* PW4      = (uint32_t*)take(2048 * 4);
    int*      part     = (int*)     take(64 * 4);

    const int BH  = (E + 2047) / 2048;             // hist blocks (8 edges/thread)
    const int BPN = (N + 255) / 256;               // node_pre blocks
    const int BZ  = 256;                           // agg-zero blocks
    const int NB  = (N + 2047) / 2048;             // scan blocks
    const int SB  = (E + 255) / 256;               // scatter blocks
    const int TB  = (NT + 255) / 256;              // ntile blocks
    const size_t zquads = (size_t)(zero_end - (char*)agg_sum) / 16;

    zero_cnt_kernel<<<(N + 255) / 256, 256, 0, stream>>>(cnt, N);
    mega_prep_kernel<<<BH + BPN + 1 + BZ, 256, 0, stream>>>(
        ei, cnt, rank, x, u, W1, b1, W2, W3, b3, W4,
        Pa, Pb, Qc, Qu, PW1, PW2, PW3, PW4,
        (uint4*)agg_sum, zquads, E, N, G, BH, BPN, BZ);
    scanA_kernel   <<<NB, 256, 0, stream>>>(cnt, part, N);
    scanC_kernel   <<<NB, 256, 0, stream>>>(cnt, part, offs, NB, N, E);
    scatter_ntile_kernel<<<SB + TB, 256, 0, stream>>>(
        ei, offs, rank, re4, ntile, E, N, NT, SB);
    fused_edge_mfma<<<(NT + 1) / 2, 128, 0, stream>>>(
        ea, PW1, PW2, b2, Pa, Pb, re4, offs, ntile, agg_sum, agg_maxb, N, E, NT);
    node_mfma      <<<(N + 127) / 128, 256, 0, stream>>>(
        Qc, Qu, batch, PW3, PW4, b4, agg_sum, agg_maxb, offs, out, N);
}